// Round 7
// baseline (347.607 us; speedup 1.0000x reference)
//
#include <hip/hip_runtime.h>
#include <math.h>

#define NN 10000
#define NE 80000
#define SF 97    // smF row stride (f32): stride%32==1 -> conflict-free per-lane rows
#define STX 72   // bf16 tile row stride (144B rows, 16B-aligned)
#define NTRI 528 // 32*33/2 unique Gram entries

typedef __attribute__((ext_vector_type(8))) __bf16 bf16x8;
typedef __attribute__((ext_vector_type(8))) short short8v;
typedef __attribute__((ext_vector_type(4))) float f32x4;
typedef __attribute__((ext_vector_type(4))) unsigned uint4v;

__device__ __forceinline__ ushort f2bf(float x) {
  union { float f; unsigned u; } v; v.f = x;
  unsigned r = v.u + 0x7FFFu + ((v.u >> 16) & 1u);
  return (ushort)(r >> 16);
}
__device__ __forceinline__ float bf2f(ushort u) {
  union { unsigned u; float f; } v; v.u = (unsigned)u << 16;
  return v.f;
}
__device__ __forceinline__ void tri_ab(int k, int& a, int& b) {
  int aa = 0, rem = k;
  while (rem >= 32 - aa) { rem -= 32 - aa; ++aa; }
  a = aa; b = aa + rem;
}

// ---- sort edges by e0 (verified R2/R3) ----
__global__ __launch_bounds__(256)
void sgnn_hist(const int* __restrict__ eidx, int* __restrict__ deg) {
  const int e = blockIdx.x * 256 + threadIdx.x;
  if (e < NE) atomicAdd(deg + eidx[e], 1);
}

__global__ __launch_bounds__(1024)
void sgnn_scan(const int* __restrict__ deg, int* __restrict__ cursor,
               int* __restrict__ start) {
  __shared__ int sm[1024];
  __shared__ int carry;
  const int t = threadIdx.x;
  if (t == 0) carry = 0;
  __syncthreads();
  for (int base = 0; base < NN; base += 1024) {
    const int i = base + t;
    const int v = (i < NN) ? deg[i] : 0;
    sm[t] = v;
    __syncthreads();
    #pragma unroll
    for (int d = 1; d < 1024; d <<= 1) {
      const int add = (t >= d) ? sm[t - d] : 0;
      __syncthreads();
      sm[t] += add;
      __syncthreads();
    }
    const int excl = carry + sm[t] - v;
    if (i < NN) { cursor[i] = excl; start[i] = excl; }
    __syncthreads();
    if (t == 1023) carry += sm[1023];
    __syncthreads();
  }
}

__global__ __launch_bounds__(256)
void sgnn_scatter(const int* __restrict__ eidx, int* __restrict__ cursor,
                  int* __restrict__ sorted) {
  const int e = blockIdx.x * 256 + threadIdx.x;
  if (e < NE) {
    const int p = atomicAdd(cursor + eidx[e], 1);
    sorted[p] = e;
  }
}

// ---- weight convert (verified R4): f32 -> blocked bf16, W1 K-folded symmetric ----
__global__ __launch_bounds__(256)
void sgnn_wconv(const float* __restrict__ nW1, const float* __restrict__ nW2,
                const float* __restrict__ nW3, const float* __restrict__ sW1,
                const float* __restrict__ sW2, const float* __restrict__ sW3,
                ushort* __restrict__ wout, ushort* __restrict__ tab) {
  const int gid = blockIdx.x * 256 + threadIdx.x;
  if (gid >= 59 * 4096) {
    const int k = gid - 59 * 4096;
    if (k < NTRI) {
      int a, b; tri_ab(k, a, b);
      tab[k] = (ushort)(a | (b << 8) | ((a != b) ? 0x8000 : 0));
    }
    return;
  }
  const int tile = gid >> 12, idx = gid & 4095;
  const int c = idx >> 6, k = idx & 63;
  float v = 0.f;
  if (tile < 12) {
    const int T = tile;
    if (T < 8 || (T == 8 && k < 16)) {
      const int ktri = T * 64 + k;
      if (ktri < NTRI) {
        int a, b; tri_ab(ktri, a, b);
        v = nW1[(a * 32 + b) * 64 + c];
        if (a != b) v += nW1[(b * 32 + a) * 64 + c];
      }
    } else if (T == 8) { if (k < 20) v = nW1[(1216 + (k - 16)) * 64 + c]; }
    else if (T == 9)   v = nW1[(1024 + k) * 64 + c];
    else if (T == 10)  v = nW1[(1088 + k) * 64 + c];
    else               v = nW1[(1152 + k) * 64 + c];
  } else if (tile == 12) v = nW2[k * 64 + c];
  else if (tile < 30)    v = nW3[k * 1088 + (tile - 13) * 64 + c];
  else if (tile < 41) {
    const int T = tile - 30;
    if (T < 8 || (T == 8 && k < 16)) {
      const int ktri = T * 64 + k;
      if (ktri < NTRI) {
        int a, b; tri_ab(ktri, a, b);
        v = sW1[(a * 32 + b) * 64 + c];
        if (a != b) v += sW1[(b * 32 + a) * 64 + c];
      }
    } else if (T == 9) v = sW1[(1024 + k) * 64 + c];
    else if (T == 10)  v = sW1[(1088 + k) * 64 + c];
  } else if (tile == 41) v = sW2[k * 64 + c];
  else                   v = sW3[k * 1088 + (tile - 42) * 64 + c];
  wout[gid] = f2bf(v);
}

#define STAGE_W(srcbase) do { const ushort* _s = (srcbase);                      \
  _Pragma("unroll") for (int rr = 0; rr < 2; ++rr) {                             \
    const int idx_ = t + 256 * rr; const int c_ = idx_ >> 3, ko_ = idx_ & 7;     \
    *(short8v*)&Wl[c_ * STX + ko_ * 8] = *(const short8v*)&_s[c_ * 64 + ko_ * 8];\
  } } while (0)

#define MFMA_K64() do {                                                          \
  _Pragma("unroll") for (int kb = 0; kb < 2; ++kb) {                             \
    const bf16x8 af_ = *(const bf16x8*)&Xl[(w * 16 + ll) * STX + kb * 32 + lh * 8]; \
    acc[0] = __builtin_amdgcn_mfma_f32_16x16x32_bf16(af_,                        \
        *(const bf16x8*)&Wl[(     ll) * STX + kb * 32 + lh * 8], acc[0], 0, 0, 0); \
    acc[1] = __builtin_amdgcn_mfma_f32_16x16x32_bf16(af_,                        \
        *(const bf16x8*)&Wl[(16 + ll) * STX + kb * 32 + lh * 8], acc[1], 0, 0, 0); \
    acc[2] = __builtin_amdgcn_mfma_f32_16x16x32_bf16(af_,                        \
        *(const bf16x8*)&Wl[(32 + ll) * STX + kb * 32 + lh * 8], acc[2], 0, 0, 0); \
    acc[3] = __builtin_amdgcn_mfma_f32_16x16x32_bf16(af_,                        \
        *(const bf16x8*)&Wl[(48 + ll) * STX + kb * 32 + lh * 8], acc[3], 0, 0, 0); \
  } } while (0)

#define ZERO_ACC() do { _Pragma("unroll") for (int q = 0; q < 4; ++q)            \
    acc[q] = (f32x4){0.f, 0.f, 0.f, 0.f}; } while (0)

// pack xv[16] (f32) -> 16 bf16 and store as 2x b128 at Xl[row j, col w*16]
#define PACK_STORE_XV() do {                                                     \
  unsigned pk[8];                                                                \
  _Pragma("unroll") for (int q = 0; q < 8; ++q)                                  \
    pk[q] = (unsigned)f2bf(xv[2 * q]) | ((unsigned)f2bf(xv[2 * q + 1]) << 16);   \
  *(uint4v*)&Xl[j * STX + w * 16]     = (uint4v){pk[0], pk[1], pk[2], pk[3]};    \
  *(uint4v*)&Xl[j * STX + w * 16 + 8] = (uint4v){pk[4], pk[5], pk[6], pk[7]};    \
} while (0)

// tri staging for 16 contiguous k starting at kt (all within tri region):
// fa cached in regs across the run; 3 ds_read per element for the b side.
#define TRI16(kt) do {                                                           \
  int prev_a = -1; float fa0 = 0.f, fa1 = 0.f, fa2 = 0.f;                        \
  _Pragma("unroll") for (int m = 0; m < 16; ++m) {                               \
    const int tb = tabL[(kt) + m];                                               \
    const int a_ = tb & 31, b_ = (tb >> 8) & 31;                                 \
    if (a_ != prev_a) { fa0 = fr[a_]; fa1 = fr[32 + a_]; fa2 = fr[64 + a_];      \
                        prev_a = a_; }                                           \
    const float v = fmaf(fa0, fr[b_],                                            \
        fmaf(fa1, fr[32 + b_], fa2 * fr[64 + b_]));                              \
    const float wsel = (tb & 0x8000) ? 2.f : 1.f;                                \
    sumsq = fmaf(v * wsel, v, sumsq);                                            \
    xv[m] = v;                                                                   \
  } } while (0)

// LDS carve (53152 B -> 3 blocks/CU)
#define LDS_BYTES 53152

__global__ __launch_bounds__(256, 3)
void sgnn_edge(const float* __restrict__ f, const float* __restrict__ s,
               const float* __restrict__ edge_f, const float* __restrict__ edge_s,
               const float* __restrict__ Wemb,
               const float* __restrict__ b1, const float* __restrict__ b2,
               const float* __restrict__ b3,
               const ushort* __restrict__ wbf, const ushort* __restrict__ tab_g,
               const int* __restrict__ eidx, const int* __restrict__ sorted,
               const int* __restrict__ start_g, const int* __restrict__ deg_g,
               float* __restrict__ fc_sum, float* __restrict__ sc_sum) {
  __shared__ __align__(16) char sbuf[LDS_BYTES];
  float*  smF  = (float*)sbuf;
  ushort* Xl   = (ushort*)(sbuf + 24832);
  ushort* Wl   = (ushort*)(sbuf + 34048);
  float*  red  = (float*)(sbuf + 43264);
  ushort* C2h  = (ushort*)(sbuf + 43264);  // bf16 [64][65]
  ushort* tabL = (ushort*)(sbuf + 51584);
  float*  iFn  = (float*)(sbuf + 51584);
  int*    es_s = (int*)(sbuf + 52640);
  ushort* e0s  = (ushort*)(sbuf + 52896);
  ushort* e1s  = (ushort*)(sbuf + 53024);
  // flush-phase overlays on dead Xl region:
  float*  fcpart = (float*)(sbuf + 24832);          // [8][96]
  float*  scpart = (float*)(sbuf + 24832 + 3072);   // [8][64]
  int*    snode  = (int*)(sbuf + 24832 + 5120);     // [8]
  int*    sst    = (int*)(sbuf + 24832 + 5152);     // [8]
  int*    sdg    = (int*)(sbuf + 24832 + 5184);     // [8]

  const int t = threadIdx.x, j = t & 63, w = t >> 6, eb = w * 16;
  const int lh = j >> 4, ll = j & 15;
  const int bid = blockIdx.x;

  if (t < 64) {
    const int e = sorted[bid * 64 + t];
    es_s[t] = e;
    e0s[t] = (ushort)eidx[e];
    e1s[t] = (ushort)eidx[NE + e];
  }
  for (int idx = t; idx < NTRI; idx += 256) tabL[idx] = tab_g[idx];
  __syncthreads();

  // per-row node extent (lane m<16 holds row eb+m's start/deg)
  int str = 0, dgr = 0;
  if (j < 16) {
    const int n_ = e0s[eb + j];
    str = start_g[n_];
    dgr = deg_g[n_];
  }

  // ---- embed (f32): Wemb column jj cached in regs (jj = t&31 is constant) ----
  {
    const int jj = t & 31;
    float Wcol[65];
    #pragma unroll
    for (int k = 0; k < 65; ++k) Wcol[k] = Wemb[k * 32 + jj];

    #pragma unroll 1
    for (int r = 0; r < 24; ++r) {
      const int out = t + 256 * r;
      const int i = (out >> 5) % 3;
      const int le = out / 96;
      const float* base0 = f + e0s[le] * 96 + i * 32;
      const float* base1 = f + e1s[le] * 96 + i * 32;
      float a = 0.f;
      #pragma unroll
      for (int kq = 0; kq < 8; ++kq) {
        const float4 v = *(const float4*)(base0 + kq * 4);
        a = fmaf(v.x, Wcol[kq * 4 + 0], a);
        a = fmaf(v.y, Wcol[kq * 4 + 1], a);
        a = fmaf(v.z, Wcol[kq * 4 + 2], a);
        a = fmaf(v.w, Wcol[kq * 4 + 3], a);
      }
      #pragma unroll
      for (int kq = 0; kq < 8; ++kq) {
        const float4 v = *(const float4*)(base1 + kq * 4);
        a = fmaf(v.x, Wcol[32 + kq * 4 + 0], a);
        a = fmaf(v.y, Wcol[32 + kq * 4 + 1], a);
        a = fmaf(v.z, Wcol[32 + kq * 4 + 2], a);
        a = fmaf(v.w, Wcol[32 + kq * 4 + 3], a);
      }
      a = fmaf(edge_f[es_s[le] * 3 + i], Wcol[64], a);
      smF[le * SF + i * 32 + jj] = a;
    }
  }

  f32x4 acc[4];
  ZERO_ACC();
  float sumsq = 0.f;

  // ---- GEMM1: 12 K-stages; thread (w,j) stages k in [w*16, w*16+16) ----
  #pragma unroll 1
  for (int T = 0; T < 12; ++T) {
    __syncthreads();
    {
      const float* fr = smF + j * SF;
      float xv[16];
      if (T < 8) {
        TRI16(T * 64 + w * 16);
      } else if (T == 8) {
        if (w == 0) {
          TRI16(512);
        } else if (w == 1) {
          const float4 v4 = *(const float4*)(edge_s + es_s[j] * 68 + 64);
          xv[0] = v4.x; xv[1] = v4.y; xv[2] = v4.z; xv[3] = v4.w;
          #pragma unroll
          for (int m = 4; m < 16; ++m) xv[m] = 0.f;
        } else {
          #pragma unroll
          for (int m = 0; m < 16; ++m) xv[m] = 0.f;
        }
      } else {
        const float* p = (T == 9)  ? (s + e0s[j] * 64 + w * 16)
                       : (T == 10) ? (s + e1s[j] * 64 + w * 16)
                                   : (edge_s + es_s[j] * 68 + w * 16);
        #pragma unroll
        for (int q = 0; q < 4; ++q) {
          const float4 v4 = *(const float4*)(p + 4 * q);
          xv[4 * q + 0] = v4.x; xv[4 * q + 1] = v4.y;
          xv[4 * q + 2] = v4.z; xv[4 * q + 3] = v4.w;
        }
      }
      PACK_STORE_XV();
    }
    STAGE_W(wbf + T * 4096);
    __syncthreads();
    MFMA_K64();
  }

  // ---- h1 epilogue + Fn reduce + W2 stage ----
  __syncthreads();
  red[w * 64 + j] = sumsq;
  #pragma unroll
  for (int nc = 0; nc < 4; ++nc) {
    const float bv = b1[nc * 16 + ll];
    #pragma unroll
    for (int r = 0; r < 4; ++r)
      Xl[(w * 16 + lh * 4 + r) * STX + nc * 16 + ll] = f2bf(fmaxf(acc[nc][r] + bv, 0.f));
  }
  STAGE_W(wbf + 12 * 4096);
  ZERO_ACC();
  __syncthreads();
  if (t < 64) {
    const float ss = red[t] + red[64 + t] + red[128 + t] + red[192 + t];
    iFn[t] = 1.f / (sqrtf(ss) + 1.f);
  }

  // ---- GEMM2 ----
  MFMA_K64();
  __syncthreads();
  #pragma unroll
  for (int nc = 0; nc < 4; ++nc) {
    const float bv = b2[nc * 16 + ll];
    #pragma unroll
    for (int r = 0; r < 4; ++r)
      Xl[(w * 16 + lh * 4 + r) * STX + nc * 16 + ll] = f2bf(fmaxf(acc[nc][r] + bv, 0.f));
  }

  // ---- GEMM3 (17 n-tiles) + fused consume ----
  float fcp[48];
  #pragma unroll
  for (int q = 0; q < 48; ++q) fcp[q] = 0.f;
  float csv[16];

  #pragma unroll 1
  for (int nt = 0; nt < 17; ++nt) {
    __syncthreads();
    STAGE_W(wbf + (13 + nt) * 4096);
    __syncthreads();
    ZERO_ACC();
    MFMA_K64();
    #pragma unroll
    for (int nc = 0; nc < 4; ++nc)
      #pragma unroll
      for (int r = 0; r < 4; ++r)
        C2h[(w * 16 + lh * 4 + r) * 65 + nc * 16 + ll] = f2bf(acc[nc][r]);
    // wave-private rows: no barrier needed before consume
    const float bv = b3[nt * 64 + j];
    if (nt < 16) {
      const int a_ = nt * 2 + (j >> 5);
      #pragma unroll
      for (int m = 0; m < 16; ++m) {
        const float cv = (bf2f(C2h[(eb + m) * 65 + j]) + bv) * iFn[eb + m];
        const float* fr = smF + (eb + m) * SF;
        fcp[m * 3 + 0] = fmaf(fr[a_],      cv, fcp[m * 3 + 0]);
        fcp[m * 3 + 1] = fmaf(fr[32 + a_], cv, fcp[m * 3 + 1]);
        fcp[m * 3 + 2] = fmaf(fr[64 + a_], cv, fcp[m * 3 + 2]);
      }
    } else {
      #pragma unroll
      for (int m = 0; m < 16; ++m)
        csv[m] = (bf2f(C2h[(eb + m) * 65 + j]) + bv) * iFn[eb + m];
    }
  }

  // ---- flush (verified R5): complete-run stores, partials via LDS merge ----
  __syncthreads();
  if (t < 8) snode[t] = -1;
  __syncthreads();

  {
    float r0 = 0.f, r1 = 0.f, r2 = 0.f, rs = 0.f;
    int runlen = 0;
    const int gwb = bid * 64 + eb;
    #pragma unroll
    for (int m = 0; m < 16; ++m) {
      float v0 = fcp[m * 3 + 0]; v0 += __shfl_xor(v0, 32);
      float v1 = fcp[m * 3 + 1]; v1 += __shfl_xor(v1, 32);
      float v2 = fcp[m * 3 + 2]; v2 += __shfl_xor(v2, 32);
      r0 += v0; r1 += v1; r2 += v2; rs += csv[m];
      ++runlen;
      const int n = e0s[eb + m];
      if (m == 15 || e0s[eb + m + 1] != n) {
        const int st = __shfl(str, m);
        const int dg = __shfl(dgr, m);
        const int g1 = gwb + m, g0 = g1 - runlen + 1;
        if (g0 == st && runlen == dg) {
          if (j < 32) {
            fc_sum[n * 96 + j]      = r0;
            fc_sum[n * 96 + 32 + j] = r1;
            fc_sum[n * 96 + 64 + j] = r2;
          }
          sc_sum[n * 64 + j] = rs;
        } else {
          const int slot = (g0 == gwb) ? 2 * w : 2 * w + 1;
          if (j < 32) {
            fcpart[slot * 96 + j]      = r0;
            fcpart[slot * 96 + 32 + j] = r1;
            fcpart[slot * 96 + 64 + j] = r2;
          }
          scpart[slot * 64 + j] = rs;
          if (j == 0) { snode[slot] = n; sst[slot] = st; sdg[slot] = dg; }
        }
        r0 = r1 = r2 = rs = 0.f; runlen = 0;
      }
    }
  }
  __syncthreads();

  if (t < 160) {
    const int ch = t;
    int prevn = -1;
    #pragma unroll 1
    for (int ss = 0; ss < 8; ++ss) {
      const int n = snode[ss];
      if (n < 0) { continue; }
      if (n != prevn) {
        float v = (ch < 96) ? fcpart[ss * 96 + ch] : scpart[ss * 64 + (ch - 96)];
        #pragma unroll 1
        for (int k2 = ss + 1; k2 < 8; ++k2) {
          if (snode[k2] == n)
            v += (ch < 96) ? fcpart[k2 * 96 + ch] : scpart[k2 * 64 + (ch - 96)];
          else if (snode[k2] >= 0) break;
        }
        const bool cib = (sst[ss] >= bid * 64) && (sst[ss] + sdg[ss] <= bid * 64 + 64);
        float* dst = (ch < 96) ? (fc_sum + n * 96 + ch) : (sc_sum + n * 64 + (ch - 96));
        if (cib) *dst = v; else atomicAdd(dst, v);
      }
      prevn = n;
    }
  }
}

// sums -> means
__global__ __launch_bounds__(256)
void sgnn_norm(float* __restrict__ fcm, float* __restrict__ scm,
               const int* __restrict__ deg) {
  const int idx = blockIdx.x * 256 + threadIdx.x;
  if (idx >= NN * 160) return;
  const int n = idx / 160, c = idx % 160;
  const float ic = 1.f / fmaxf((float)deg[n], 1.f);
  if (c < 96) fcm[n * 96 + c] *= ic;
  else        scm[n * 64 + (c - 96)] *= ic;
}

__global__ __launch_bounds__(256, 3)
void sgnn_node(const float* __restrict__ f, const float* __restrict__ s,
               const float* __restrict__ Wemb,
               const float* __restrict__ b1, const float* __restrict__ b2,
               const float* __restrict__ b3,
               const ushort* __restrict__ wbf, const ushort* __restrict__ tab_g,
               const float* __restrict__ fcm, const float* __restrict__ scm,
               float* __restrict__ of, float* __restrict__ os) {
  __shared__ __align__(16) char sbuf[LDS_BYTES];
  float*  smF  = (float*)sbuf;
  ushort* Xl   = (ushort*)(sbuf + 24832);
  ushort* Wl   = (ushort*)(sbuf + 34048);
  float*  red  = (float*)(sbuf + 43264);
  ushort* C2h  = (ushort*)(sbuf + 43264);
  ushort* tabL = (ushort*)(sbuf + 51584);
  float*  iFn  = (float*)(sbuf + 51584);

  const int t = threadIdx.x, j = t & 63, w = t >> 6, eb = w * 16;
  const int lh = j >> 4, ll = j & 15;
  const int nbase = blockIdx.x * 64;

  for (int idx = t; idx < NTRI; idx += 256) tabL[idx] = tab_g[idx];
  __syncthreads();

  // ---- embed: tf = concat(f, f_c_mean) @ Wemb2, W column in regs ----
  {
    const int jj = t & 31;
    float Wcol[64];
    #pragma unroll
    for (int k = 0; k < 64; ++k) Wcol[k] = Wemb[k * 32 + jj];

    #pragma unroll 1
    for (int r = 0; r < 24; ++r) {
      const int out = t + 256 * r;
      const int i = (out >> 5) % 3;
      const int le = out / 96;
      const int nc = min(nbase + le, NN - 1);
      const float* base0 = f + nc * 96 + i * 32;
      const float* basec = fcm + nc * 96 + i * 32;
      float a = 0.f;
      #pragma unroll
      for (int kq = 0; kq < 8; ++kq) {
        const float4 v = *(const float4*)(base0 + kq * 4);
        a = fmaf(v.x, Wcol[kq * 4 + 0], a);
        a = fmaf(v.y, Wcol[kq * 4 + 1], a);
        a = fmaf(v.z, Wcol[kq * 4 + 2], a);
        a = fmaf(v.w, Wcol[kq * 4 + 3], a);
      }
      #pragma unroll
      for (int kq = 0; kq < 8; ++kq) {
        const float4 v = *(const float4*)(basec + kq * 4);
        a = fmaf(v.x, Wcol[32 + kq * 4 + 0], a);
        a = fmaf(v.y, Wcol[32 + kq * 4 + 1], a);
        a = fmaf(v.z, Wcol[32 + kq * 4 + 2], a);
        a = fmaf(v.w, Wcol[32 + kq * 4 + 3], a);
      }
      smF[le * SF + i * 32 + jj] = a;
    }
  }

  f32x4 acc[4];
  ZERO_ACC();
  float sumsq = 0.f;

  // ---- GEMM1: 11 K-stages ----
  #pragma unroll 1
  for (int T = 0; T < 11; ++T) {
    __syncthreads();
    {
      const int nc = min(nbase + j, NN - 1);
      const float* fr = smF + j * SF;
      float xv[16];
      if (T < 8) {
        TRI16(T * 64 + w * 16);
      } else if (T == 8) {
        if (w == 0) {
          TRI16(512);
        } else {
          #pragma unroll
          for (int m = 0; m < 16; ++m) xv[m] = 0.f;
        }
      } else {
        const float* p = (T == 9) ? (s + nc * 64 + w * 16)
                                  : (scm + nc * 64 + w * 16);
        #pragma unroll
        for (int q = 0; q < 4; ++q) {
          const float4 v4 = *(const float4*)(p + 4 * q);
          xv[4 * q + 0] = v4.x; xv[4 * q + 1] = v4.y;
          xv[4 * q + 2] = v4.z; xv[4 * q + 3] = v4.w;
        }
      }
      PACK_STORE_XV();
    }
    STAGE_W(wbf + (30 + T) * 4096);
    __syncthreads();
    MFMA_K64();
  }

  __syncthreads();
  red[w * 64 + j] = sumsq;
  #pragma unroll
  for (int nc = 0; nc < 4; ++nc) {
    const float bv = b1[nc * 16 + ll];
    #pragma unroll
    for (int r = 0; r < 4; ++r)
      Xl[(w * 16 + lh * 4 + r) * STX + nc * 16 + ll] = f2bf(fmaxf(acc[nc][r] + bv, 0.f));
  }
  STAGE_W(wbf + 41 * 4096);
  ZERO_ACC();
  __syncthreads();
  if (t < 64) {
    const float ss = red[t] + red[64 + t] + red[128 + t] + red[192 + t];
    iFn[t] = 1.f / (sqrtf(ss) + 1.f);
  }

  MFMA_K64();
  __syncthreads();
  #pragma unroll
  for (int nc = 0; nc < 4; ++nc) {
    const float bv = b2[nc * 16 + ll];
    #pragma unroll
    for (int r = 0; r < 4; ++r)
      Xl[(w * 16 + lh * 4 + r) * STX + nc * 16 + ll] = f2bf(fmaxf(acc[nc][r] + bv, 0.f));
  }

  float fcp[48];
  #pragma unroll
  for (int q = 0; q < 48; ++q) fcp[q] = 0.f;

  #pragma unroll 1
  for (int nt = 0; nt < 17; ++nt) {
    __syncthreads();
    STAGE_W(wbf + (42 + nt) * 4096);
    __syncthreads();
    ZERO_ACC();
    MFMA_K64();
    #pragma unroll
    for (int nc = 0; nc < 4; ++nc)
      #pragma unroll
      for (int r = 0; r < 4; ++r)
        C2h[(w * 16 + lh * 4 + r) * 65 + nc * 16 + ll] = f2bf(acc[nc][r]);
    const float bv = b3[nt * 64 + j];
    if (nt < 16) {
      const int a_ = nt * 2 + (j >> 5);
      #pragma unroll
      for (int m = 0; m < 16; ++m) {
        const float cv = (bf2f(C2h[(eb + m) * 65 + j]) + bv) * iFn[eb + m];
        const float* fr = smF + (eb + m) * SF;
        fcp[m * 3 + 0] = fmaf(fr[a_],      cv, fcp[m * 3 + 0]);
        fcp[m * 3 + 1] = fmaf(fr[32 + a_], cv, fcp[m * 3 + 1]);
        fcp[m * 3 + 2] = fmaf(fr[64 + a_], cv, fcp[m * 3 + 2]);
      }
    } else {
      #pragma unroll 1
      for (int m = 0; m < 16; ++m) {
        const int n_m = nbase + eb + m;
        const float cv = (bf2f(C2h[(eb + m) * 65 + j]) + bv) * iFn[eb + m];
        if (n_m < NN) os[n_m * 64 + j] = cv + s[n_m * 64 + j];
      }
    }
  }

  {
    const int b_ = j & 31;
    #pragma unroll
    for (int m = 0; m < 16; ++m) {
      const int n_m = nbase + eb + m;
      #pragma unroll
      for (int i = 0; i < 3; ++i) {
        float v = fcp[m * 3 + i];
        v += __shfl_xor(v, 32);
        if (j < 32 && n_m < NN)
          of[n_m * 96 + i * 32 + b_] = v + f[n_m * 96 + i * 32 + b_];
      }
    }
  }
}

extern "C" void kernel_launch(void* const* d_in, const int* in_sizes, int n_in,
                              void* d_out, int out_size, void* d_ws, size_t ws_size,
                              hipStream_t stream) {
  const float* f      = (const float*)d_in[0];
  const float* s      = (const float*)d_in[1];
  const float* edge_f = (const float*)d_in[2];
  const float* edge_s = (const float*)d_in[3];
  const float* Wemb1  = (const float*)d_in[4];
  const float* nW1 = (const float*)d_in[5];
  const float* nb1 = (const float*)d_in[6];
  const float* nW2 = (const float*)d_in[7];
  const float* nb2 = (const float*)d_in[8];
  const float* nW3 = (const float*)d_in[9];
  const float* nb3 = (const float*)d_in[10];
  const float* Wemb2 = (const float*)d_in[11];
  const float* sW1 = (const float*)d_in[12];
  const float* sb1 = (const float*)d_in[13];
  const float* sW2 = (const float*)d_in[14];
  const float* sb2 = (const float*)d_in[15];
  const float* sW3 = (const float*)d_in[16];
  const float* sb3 = (const float*)d_in[17];
  const int* eidx  = (const int*)d_in[18];

  float* of = (float*)d_out;               // [NN*96] ; aliases fc mean
  float* os = of + (size_t)NN * 96;        // [NN*64] ; aliases sc mean

  // ws: deg[NN] | cursor[NN] | start[NN] | sorted[NE] | wbf[59*4096] | tab[528]
  int* deg    = (int*)d_ws;
  int* cursor = deg + NN;
  int* start  = cursor + NN;
  int* sorted = start + NN;
  ushort* wbf = (ushort*)(sorted + NE);
  ushort* tab = wbf + 59 * 4096;

  hipMemsetAsync(deg, 0, (size_t)NN * 4, stream);
  hipMemsetAsync(d_out, 0, (size_t)NN * 160 * 4, stream);

  hipLaunchKernelGGL(sgnn_wconv, dim3((59 * 4096 + NTRI + 255) / 256), dim3(256),
                     0, stream, nW1, nW2, nW3, sW1, sW2, sW3, wbf, tab);
  hipLaunchKernelGGL(sgnn_hist, dim3((NE + 255) / 256), dim3(256), 0, stream,
                     eidx, deg);
  hipLaunchKernelGGL(sgnn_scan, dim3(1), dim3(1024), 0, stream, deg, cursor, start);
  hipLaunchKernelGGL(sgnn_scatter, dim3((NE + 255) / 256), dim3(256), 0, stream,
                     eidx, cursor, sorted);
  hipLaunchKernelGGL(sgnn_edge, dim3(NE / 64), dim3(256), 0, stream,
                     f, s, edge_f, edge_s, Wemb1, nb1, nb2, nb3,
                     wbf, tab, eidx, sorted, start, deg,
                     of /*fc_sum*/, os /*sc_sum*/);
  hipLaunchKernelGGL(sgnn_norm, dim3((NN * 160 + 255) / 256), dim3(256), 0, stream,
                     of, os, deg);
  hipLaunchKernelGGL(sgnn_node, dim3((NN + 63) / 64), dim3(256), 0, stream,
                     f, s, Wemb2, sb1, sb2, sb3,
                     wbf, tab, of /*fcm*/, os /*scm*/, of, os);
}

// Round 8
// 325.907 us; speedup vs baseline: 1.0666x; 1.0666x over previous
//
#include <hip/hip_runtime.h>
#include <math.h>

#define NN 10000
#define NE 80000
#define SF 97    // smF row stride (f32): stride%32==1 -> conflict-free per-lane rows
#define STX 72   // bf16 tile row stride (144B rows, 16B-aligned)
#define NTRI 528 // 32*33/2 unique Gram entries

typedef __attribute__((ext_vector_type(8))) __bf16 bf16x8;
typedef __attribute__((ext_vector_type(8))) short short8v;
typedef __attribute__((ext_vector_type(4))) float f32x4;
typedef __attribute__((ext_vector_type(4))) unsigned uint4v;

__device__ __forceinline__ ushort f2bf(float x) {
  union { float f; unsigned u; } v; v.f = x;
  unsigned r = v.u + 0x7FFFu + ((v.u >> 16) & 1u);
  return (ushort)(r >> 16);
}
__device__ __forceinline__ float bf2f(ushort u) {
  union { unsigned u; float f; } v; v.u = (unsigned)u << 16;
  return v.f;
}
__device__ __forceinline__ void tri_ab(int k, int& a, int& b) {
  int aa = 0, rem = k;
  while (rem >= 32 - aa) { rem -= 32 - aa; ++aa; }
  a = aa; b = aa + rem;
}

// ---- sort edges by e0 (verified R2/R3) ----
__global__ __launch_bounds__(256)
void sgnn_hist(const int* __restrict__ eidx, int* __restrict__ deg) {
  const int e = blockIdx.x * 256 + threadIdx.x;
  if (e < NE) atomicAdd(deg + eidx[e], 1);
}

__global__ __launch_bounds__(1024)
void sgnn_scan(const int* __restrict__ deg, int* __restrict__ cursor,
               int* __restrict__ start) {
  __shared__ int sm[1024];
  __shared__ int carry;
  const int t = threadIdx.x;
  if (t == 0) carry = 0;
  __syncthreads();
  for (int base = 0; base < NN; base += 1024) {
    const int i = base + t;
    const int v = (i < NN) ? deg[i] : 0;
    sm[t] = v;
    __syncthreads();
    #pragma unroll
    for (int d = 1; d < 1024; d <<= 1) {
      const int add = (t >= d) ? sm[t - d] : 0;
      __syncthreads();
      sm[t] += add;
      __syncthreads();
    }
    const int excl = carry + sm[t] - v;
    if (i < NN) { cursor[i] = excl; start[i] = excl; }
    __syncthreads();
    if (t == 1023) carry += sm[1023];
    __syncthreads();
  }
}

__global__ __launch_bounds__(256)
void sgnn_scatter(const int* __restrict__ eidx, int* __restrict__ cursor,
                  int* __restrict__ sorted) {
  const int e = blockIdx.x * 256 + threadIdx.x;
  if (e < NE) {
    const int p = atomicAdd(cursor + eidx[e], 1);
    sorted[p] = e;
  }
}

// ---- weight convert (verified R4): f32 -> blocked bf16, W1 K-folded symmetric ----
__global__ __launch_bounds__(256)
void sgnn_wconv(const float* __restrict__ nW1, const float* __restrict__ nW2,
                const float* __restrict__ nW3, const float* __restrict__ sW1,
                const float* __restrict__ sW2, const float* __restrict__ sW3,
                ushort* __restrict__ wout, ushort* __restrict__ tab) {
  const int gid = blockIdx.x * 256 + threadIdx.x;
  if (gid >= 59 * 4096) {
    const int k = gid - 59 * 4096;
    if (k < NTRI) {
      int a, b; tri_ab(k, a, b);
      tab[k] = (ushort)(a | (b << 8) | ((a != b) ? 0x8000 : 0));
    }
    return;
  }
  const int tile = gid >> 12, idx = gid & 4095;
  const int c = idx >> 6, k = idx & 63;
  float v = 0.f;
  if (tile < 12) {
    const int T = tile;
    if (T < 8 || (T == 8 && k < 16)) {
      const int ktri = T * 64 + k;
      if (ktri < NTRI) {
        int a, b; tri_ab(ktri, a, b);
        v = nW1[(a * 32 + b) * 64 + c];
        if (a != b) v += nW1[(b * 32 + a) * 64 + c];
      }
    } else if (T == 8) { if (k < 20) v = nW1[(1216 + (k - 16)) * 64 + c]; }
    else if (T == 9)   v = nW1[(1024 + k) * 64 + c];
    else if (T == 10)  v = nW1[(1088 + k) * 64 + c];
    else               v = nW1[(1152 + k) * 64 + c];
  } else if (tile == 12) v = nW2[k * 64 + c];
  else if (tile < 30)    v = nW3[k * 1088 + (tile - 13) * 64 + c];
  else if (tile < 41) {
    const int T = tile - 30;
    if (T < 8 || (T == 8 && k < 16)) {
      const int ktri = T * 64 + k;
      if (ktri < NTRI) {
        int a, b; tri_ab(ktri, a, b);
        v = sW1[(a * 32 + b) * 64 + c];
        if (a != b) v += sW1[(b * 32 + a) * 64 + c];
      }
    } else if (T == 9) v = sW1[(1024 + k) * 64 + c];
    else if (T == 10)  v = sW1[(1088 + k) * 64 + c];
  } else if (tile == 41) v = sW2[k * 64 + c];
  else                   v = sW3[k * 1088 + (tile - 42) * 64 + c];
  wout[gid] = f2bf(v);
}

// W-tile prefetch: global -> regs (issue early), regs -> LDS (write late, T14)
#define WPRE_LOAD(srcbase) do { const ushort* _s = (srcbase);                    \
  wpre0 = *(const short8v*)&_s[(t >> 3) * 64 + (t & 7) * 8];                     \
  wpre1 = *(const short8v*)&_s[(32 + (t >> 3)) * 64 + (t & 7) * 8]; } while (0)

#define WPRE_STORE() do {                                                        \
  *(short8v*)&Wl[(t >> 3) * STX + (t & 7) * 8] = wpre0;                          \
  *(short8v*)&Wl[(32 + (t >> 3)) * STX + (t & 7) * 8] = wpre1; } while (0)

#define MFMA_K64() do {                                                          \
  _Pragma("unroll") for (int kb = 0; kb < 2; ++kb) {                             \
    const bf16x8 af_ = *(const bf16x8*)&Xl[(w * 16 + ll) * STX + kb * 32 + lh * 8]; \
    acc[0] = __builtin_amdgcn_mfma_f32_16x16x32_bf16(af_,                        \
        *(const bf16x8*)&Wl[(     ll) * STX + kb * 32 + lh * 8], acc[0], 0, 0, 0); \
    acc[1] = __builtin_amdgcn_mfma_f32_16x16x32_bf16(af_,                        \
        *(const bf16x8*)&Wl[(16 + ll) * STX + kb * 32 + lh * 8], acc[1], 0, 0, 0); \
    acc[2] = __builtin_amdgcn_mfma_f32_16x16x32_bf16(af_,                        \
        *(const bf16x8*)&Wl[(32 + ll) * STX + kb * 32 + lh * 8], acc[2], 0, 0, 0); \
    acc[3] = __builtin_amdgcn_mfma_f32_16x16x32_bf16(af_,                        \
        *(const bf16x8*)&Wl[(48 + ll) * STX + kb * 32 + lh * 8], acc[3], 0, 0, 0); \
  } } while (0)

#define ZERO_ACC() do { _Pragma("unroll") for (int q = 0; q < 4; ++q)            \
    acc[q] = (f32x4){0.f, 0.f, 0.f, 0.f}; } while (0)

// pack xv[16] (f32) -> 16 bf16, store as 2x b128 at Xl[row j, col w*16]
#define PACK_STORE_XV() do {                                                     \
  unsigned pk[8];                                                                \
  _Pragma("unroll") for (int q = 0; q < 8; ++q)                                  \
    pk[q] = (unsigned)f2bf(xv[2 * q]) | ((unsigned)f2bf(xv[2 * q + 1]) << 16);   \
  *(uint4v*)&Xl[j * STX + w * 16]     = (uint4v){pk[0], pk[1], pk[2], pk[3]};    \
  *(uint4v*)&Xl[j * STX + w * 16 + 8] = (uint4v){pk[4], pk[5], pk[6], pk[7]};    \
} while (0)

// tri staging for 16 contiguous k starting at kt; fa cached across runs
#define TRI16(kt) do {                                                           \
  int prev_a = -1; float fa0 = 0.f, fa1 = 0.f, fa2 = 0.f;                        \
  _Pragma("unroll") for (int m = 0; m < 16; ++m) {                               \
    const int tb = tabL[(kt) + m];                                               \
    const int a_ = tb & 31, b_ = (tb >> 8) & 31;                                 \
    if (a_ != prev_a) { fa0 = fr[a_]; fa1 = fr[32 + a_]; fa2 = fr[64 + a_];      \
                        prev_a = a_; }                                           \
    const float v = fmaf(fa0, fr[b_],                                            \
        fmaf(fa1, fr[32 + b_], fa2 * fr[64 + b_]));                              \
    const float wsel = (tb & 0x8000) ? 2.f : 1.f;                                \
    sumsq = fmaf(v * wsel, v, sumsq);                                            \
    xv[m] = v;                                                                   \
  } } while (0)

#define XV_FROM_F4(arr) do { _Pragma("unroll") for (int q = 0; q < 4; ++q) {     \
    xv[4 * q + 0] = arr[q].x; xv[4 * q + 1] = arr[q].y;                          \
    xv[4 * q + 2] = arr[q].z; xv[4 * q + 3] = arr[q].w; } } while (0)

// LDS carve (53152 B -> 3 blocks/CU)
#define LDS_BYTES 53152

__global__ __launch_bounds__(256, 3)
void sgnn_edge(const float* __restrict__ f, const float* __restrict__ s,
               const float* __restrict__ edge_f, const float* __restrict__ edge_s,
               const float* __restrict__ Wemb,
               const float* __restrict__ b1, const float* __restrict__ b2,
               const float* __restrict__ b3,
               const ushort* __restrict__ wbf, const ushort* __restrict__ tab_g,
               const int* __restrict__ eidx, const int* __restrict__ sorted,
               const int* __restrict__ start_g, const int* __restrict__ deg_g,
               float* __restrict__ fc_sum, float* __restrict__ sc_sum) {
  __shared__ __align__(16) char sbuf[LDS_BYTES];
  float*  smF  = (float*)sbuf;
  ushort* Xl   = (ushort*)(sbuf + 24832);
  ushort* Wl   = (ushort*)(sbuf + 34048);
  float*  R1f  = (float*)(sbuf + 43264);   // WembL(embed) / red(postG1)
  ushort* C2h  = (ushort*)(sbuf + 43264);  // bf16 [64][65] (G3)
  ushort* tabL = (ushort*)(sbuf + 51584);
  float*  iFn  = (float*)(sbuf + 51584);   // overlays tab after GEMM1
  int*    es_s = (int*)(sbuf + 52640);
  ushort* e0s  = (ushort*)(sbuf + 52896);
  ushort* e1s  = (ushort*)(sbuf + 53024);
  // flush-phase overlays on dead Xl region:
  float*  fcpart = (float*)(sbuf + 24832);          // [8][96]
  float*  scpart = (float*)(sbuf + 24832 + 3072);   // [8][64]
  int*    snode  = (int*)(sbuf + 24832 + 5120);     // [8]
  int*    sst    = (int*)(sbuf + 24832 + 5152);     // [8]
  int*    sdg    = (int*)(sbuf + 24832 + 5184);     // [8]

  const int t = threadIdx.x, j = t & 63, w = t >> 6, eb = w * 16;
  const int lh = j >> 4, ll = j & 15;
  const int bid = blockIdx.x;
  float* WembL = R1f;
  float* red   = R1f;
  short8v wpre0, wpre1;

  if (t < 64) {
    const int e = sorted[bid * 64 + t];
    es_s[t] = e;
    e0s[t] = (ushort)eidx[e];
    e1s[t] = (ushort)eidx[NE + e];
  }
  for (int idx = t; idx < NTRI; idx += 256) tabL[idx] = tab_g[idx];
  for (int idx = t; idx < 65 * 32; idx += 256) WembL[idx] = Wemb[idx];
  __syncthreads();

  // per-row node extent (lane m<16 holds row eb+m's start/deg)
  int str = 0, dgr = 0;
  if (j < 16) {
    const int n_ = e0s[eb + j];
    str = start_g[n_];
    dgr = deg_g[n_];
  }

  // hoisted gathers for stages 8(tail)/9/10/11 — latency hides under embed
  float4 g0[4], g1[4], ge[4], get;
  {
    const float* p0 = s + e0s[j] * 64 + w * 16;
    const float* p1 = s + e1s[j] * 64 + w * 16;
    const float* pe = edge_s + es_s[j] * 68 + w * 16;
    #pragma unroll
    for (int q = 0; q < 4; ++q) {
      g0[q] = *(const float4*)(p0 + 4 * q);
      g1[q] = *(const float4*)(p1 + 4 * q);
      ge[q] = *(const float4*)(pe + 4 * q);
    }
    get = *(const float4*)(edge_s + es_s[j] * 68 + 64);
  }
  WPRE_LOAD(wbf + 0);

  // ---- embed (f32): WembL broadcast reads; 4 accums break the fma chain ----
  #pragma unroll 1
  for (int r = 0; r < 24; ++r) {
    const int out = t + 256 * r;
    const int jj = out & 31;
    const int i = (out >> 5) % 3;
    const int le = out / 96;
    const float* base0 = f + e0s[le] * 96 + i * 32;
    const float* base1 = f + e1s[le] * 96 + i * 32;
    float a0 = 0.f, a1 = 0.f, a2 = 0.f, a3 = 0.f;
    #pragma unroll
    for (int kq = 0; kq < 8; ++kq) {
      const float4 v = *(const float4*)(base0 + kq * 4);
      a0 = fmaf(v.x, WembL[(kq * 4 + 0) * 32 + jj], a0);
      a1 = fmaf(v.y, WembL[(kq * 4 + 1) * 32 + jj], a1);
      a2 = fmaf(v.z, WembL[(kq * 4 + 2) * 32 + jj], a2);
      a3 = fmaf(v.w, WembL[(kq * 4 + 3) * 32 + jj], a3);
    }
    #pragma unroll
    for (int kq = 0; kq < 8; ++kq) {
      const float4 v = *(const float4*)(base1 + kq * 4);
      a0 = fmaf(v.x, WembL[(32 + kq * 4 + 0) * 32 + jj], a0);
      a1 = fmaf(v.y, WembL[(32 + kq * 4 + 1) * 32 + jj], a1);
      a2 = fmaf(v.z, WembL[(32 + kq * 4 + 2) * 32 + jj], a2);
      a3 = fmaf(v.w, WembL[(32 + kq * 4 + 3) * 32 + jj], a3);
    }
    a0 = fmaf(edge_f[es_s[le] * 3 + i], WembL[64 * 32 + jj], a0);
    smF[le * SF + i * 32 + jj] = (a0 + a1) + (a2 + a3);
  }

  f32x4 acc[4];
  ZERO_ACC();
  float sumsq = 0.f;

  // ---- GEMM1: 12 K-stages; W(T) via reg-prefetch, X(T) staged in-phase ----
  #pragma unroll 1
  for (int T = 0; T < 12; ++T) {
    __syncthreads();                 // prior MFMA done reading Xl/Wl
    WPRE_STORE();                    // W(T) regs -> Wl
    {
      const float* fr = smF + j * SF;
      float xv[16];
      if (T < 8) {
        TRI16(T * 64 + w * 16);
      } else if (T == 8) {
        if (w == 0) {
          TRI16(512);
        } else if (w == 1) {
          xv[0] = get.x; xv[1] = get.y; xv[2] = get.z; xv[3] = get.w;
          #pragma unroll
          for (int m = 4; m < 16; ++m) xv[m] = 0.f;
        } else {
          #pragma unroll
          for (int m = 0; m < 16; ++m) xv[m] = 0.f;
        }
      } else if (T == 9)  { XV_FROM_F4(g0); }
      else if (T == 10)   { XV_FROM_F4(g1); }
      else                { XV_FROM_F4(ge); }
      PACK_STORE_XV();
    }
    __syncthreads();
    WPRE_LOAD(wbf + (T + 1) * 4096); // T=11 -> tile 12 (W2); hides under MFMA
    MFMA_K64();
  }

  // ---- h1 epilogue + Fn reduce + W2 via prefetch ----
  __syncthreads();
  red[w * 64 + j] = sumsq;
  #pragma unroll
  for (int nc = 0; nc < 4; ++nc) {
    const float bv = b1[nc * 16 + ll];
    #pragma unroll
    for (int r = 0; r < 4; ++r)
      Xl[(w * 16 + lh * 4 + r) * STX + nc * 16 + ll] = f2bf(fmaxf(acc[nc][r] + bv, 0.f));
  }
  WPRE_STORE();                      // W2 -> Wl
  ZERO_ACC();
  __syncthreads();
  WPRE_LOAD(wbf + 13 * 4096);        // GEMM3 nt=0 tile
  if (t < 64) {
    const float ss = red[t] + red[64 + t] + red[128 + t] + red[192 + t];
    iFn[t] = 1.f / (sqrtf(ss) + 1.f);
  }

  // ---- GEMM2 (h1 strip is wave-local; only Wl needed the barrier) ----
  MFMA_K64();
  #pragma unroll
  for (int nc = 0; nc < 4; ++nc) {
    const float bv = b2[nc * 16 + ll];
    #pragma unroll
    for (int r = 0; r < 4; ++r)
      Xl[(w * 16 + lh * 4 + r) * STX + nc * 16 + ll] = f2bf(fmaxf(acc[nc][r] + bv, 0.f));
  }

  // ---- GEMM3 (17 n-tiles) + fused consume; W(nt+1) prefetch hides under consume
  float fcp[48];
  #pragma unroll
  for (int q = 0; q < 48; ++q) fcp[q] = 0.f;
  float csv[16];

  #pragma unroll 1
  for (int nt = 0; nt < 17; ++nt) {
    __syncthreads();                 // all waves done reading Wl (prev MFMA)
    WPRE_STORE();                    // W(13+nt)
    __syncthreads();
    if (nt < 16) WPRE_LOAD(wbf + (14 + nt) * 4096);
    ZERO_ACC();
    MFMA_K64();
    #pragma unroll
    for (int nc = 0; nc < 4; ++nc)
      #pragma unroll
      for (int r = 0; r < 4; ++r)
        C2h[(w * 16 + lh * 4 + r) * 65 + nc * 16 + ll] = f2bf(acc[nc][r]);
    // wave-private rows: no barrier needed before consume
    const float bv = b3[nt * 64 + j];
    if (nt < 16) {
      const int a_ = nt * 2 + (j >> 5);
      #pragma unroll
      for (int m = 0; m < 16; ++m) {
        const float cv = (bf2f(C2h[(eb + m) * 65 + j]) + bv) * iFn[eb + m];
        const float* fr = smF + (eb + m) * SF;
        fcp[m * 3 + 0] = fmaf(fr[a_],      cv, fcp[m * 3 + 0]);
        fcp[m * 3 + 1] = fmaf(fr[32 + a_], cv, fcp[m * 3 + 1]);
        fcp[m * 3 + 2] = fmaf(fr[64 + a_], cv, fcp[m * 3 + 2]);
      }
    } else {
      #pragma unroll
      for (int m = 0; m < 16; ++m)
        csv[m] = (bf2f(C2h[(eb + m) * 65 + j]) + bv) * iFn[eb + m];
    }
  }

  // ---- flush (verified R5): complete-run stores, partials via LDS merge ----
  __syncthreads();
  if (t < 8) snode[t] = -1;
  __syncthreads();

  {
    float r0 = 0.f, r1 = 0.f, r2 = 0.f, rs = 0.f;
    int runlen = 0;
    const int gwb = bid * 64 + eb;
    #pragma unroll
    for (int m = 0; m < 16; ++m) {
      float v0 = fcp[m * 3 + 0]; v0 += __shfl_xor(v0, 32);
      float v1 = fcp[m * 3 + 1]; v1 += __shfl_xor(v1, 32);
      float v2 = fcp[m * 3 + 2]; v2 += __shfl_xor(v2, 32);
      r0 += v0; r1 += v1; r2 += v2; rs += csv[m];
      ++runlen;
      const int n = e0s[eb + m];
      if (m == 15 || e0s[eb + m + 1] != n) {
        const int st = __shfl(str, m);
        const int dg = __shfl(dgr, m);
        const int g1v = gwb + m, g0v = g1v - runlen + 1;
        if (g0v == st && runlen == dg) {
          if (j < 32) {
            fc_sum[n * 96 + j]      = r0;
            fc_sum[n * 96 + 32 + j] = r1;
            fc_sum[n * 96 + 64 + j] = r2;
          }
          sc_sum[n * 64 + j] = rs;
        } else {
          const int slot = (g0v == gwb) ? 2 * w : 2 * w + 1;
          if (j < 32) {
            fcpart[slot * 96 + j]      = r0;
            fcpart[slot * 96 + 32 + j] = r1;
            fcpart[slot * 96 + 64 + j] = r2;
          }
          scpart[slot * 64 + j] = rs;
          if (j == 0) { snode[slot] = n; sst[slot] = st; sdg[slot] = dg; }
        }
        r0 = r1 = r2 = rs = 0.f; runlen = 0;
      }
    }
  }
  __syncthreads();

  if (t < 160) {
    const int ch = t;
    int prevn = -1;
    #pragma unroll 1
    for (int ss = 0; ss < 8; ++ss) {
      const int n = snode[ss];
      if (n < 0) { continue; }
      if (n != prevn) {
        float v = (ch < 96) ? fcpart[ss * 96 + ch] : scpart[ss * 64 + (ch - 96)];
        #pragma unroll 1
        for (int k2 = ss + 1; k2 < 8; ++k2) {
          if (snode[k2] == n)
            v += (ch < 96) ? fcpart[k2 * 96 + ch] : scpart[k2 * 64 + (ch - 96)];
          else if (snode[k2] >= 0) break;
        }
        const bool cib = (sst[ss] >= bid * 64) && (sst[ss] + sdg[ss] <= bid * 64 + 64);
        float* dst = (ch < 96) ? (fc_sum + n * 96 + ch) : (sc_sum + n * 64 + (ch - 96));
        if (cib) *dst = v; else atomicAdd(dst, v);
      }
      prevn = n;
    }
  }
}

// sums -> means
__global__ __launch_bounds__(256)
void sgnn_norm(float* __restrict__ fcm, float* __restrict__ scm,
               const int* __restrict__ deg) {
  const int idx = blockIdx.x * 256 + threadIdx.x;
  if (idx >= NN * 160) return;
  const int n = idx / 160, c = idx % 160;
  const float ic = 1.f / fmaxf((float)deg[n], 1.f);
  if (c < 96) fcm[n * 96 + c] *= ic;
  else        scm[n * 64 + (c - 96)] *= ic;
}

__global__ __launch_bounds__(256, 3)
void sgnn_node(const float* __restrict__ f, const float* __restrict__ s,
               const float* __restrict__ Wemb,
               const float* __restrict__ b1, const float* __restrict__ b2,
               const float* __restrict__ b3,
               const ushort* __restrict__ wbf, const ushort* __restrict__ tab_g,
               const float* __restrict__ fcm, const float* __restrict__ scm,
               float* __restrict__ of, float* __restrict__ os) {
  __shared__ __align__(16) char sbuf[LDS_BYTES];
  float*  smF  = (float*)sbuf;
  ushort* Xl   = (ushort*)(sbuf + 24832);
  ushort* Wl   = (ushort*)(sbuf + 34048);
  float*  R1f  = (float*)(sbuf + 43264);
  ushort* C2h  = (ushort*)(sbuf + 43264);
  ushort* tabL = (ushort*)(sbuf + 51584);
  float*  iFn  = (float*)(sbuf + 51584);

  const int t = threadIdx.x, j = t & 63, w = t >> 6, eb = w * 16;
  const int lh = j >> 4, ll = j & 15;
  const int nbase = blockIdx.x * 64;
  float* WembL = R1f;
  float* red   = R1f;
  short8v wpre0, wpre1;

  for (int idx = t; idx < NTRI; idx += 256) tabL[idx] = tab_g[idx];
  for (int idx = t; idx < 64 * 32; idx += 256) WembL[idx] = Wemb[idx];

  // hoisted gathers for stages 9/10 (own-row s, scm); no LDS dependency
  float4 gs[4], gc[4];
  {
    const int nc = min(nbase + j, NN - 1);
    const float* ps = s   + nc * 64 + w * 16;
    const float* pc = scm + nc * 64 + w * 16;
    #pragma unroll
    for (int q = 0; q < 4; ++q) {
      gs[q] = *(const float4*)(ps + 4 * q);
      gc[q] = *(const float4*)(pc + 4 * q);
    }
  }
  WPRE_LOAD(wbf + 30 * 4096);
  __syncthreads();

  // ---- embed: tf = concat(f, f_c_mean) @ Wemb2 ----
  #pragma unroll 1
  for (int r = 0; r < 24; ++r) {
    const int out = t + 256 * r;
    const int jj = out & 31;
    const int i = (out >> 5) % 3;
    const int le = out / 96;
    const int nc = min(nbase + le, NN - 1);
    const float* base0 = f + nc * 96 + i * 32;
    const float* basec = fcm + nc * 96 + i * 32;
    float a0 = 0.f, a1 = 0.f, a2 = 0.f, a3 = 0.f;
    #pragma unroll
    for (int kq = 0; kq < 8; ++kq) {
      const float4 v = *(const float4*)(base0 + kq * 4);
      a0 = fmaf(v.x, WembL[(kq * 4 + 0) * 32 + jj], a0);
      a1 = fmaf(v.y, WembL[(kq * 4 + 1) * 32 + jj], a1);
      a2 = fmaf(v.z, WembL[(kq * 4 + 2) * 32 + jj], a2);
      a3 = fmaf(v.w, WembL[(kq * 4 + 3) * 32 + jj], a3);
    }
    #pragma unroll
    for (int kq = 0; kq < 8; ++kq) {
      const float4 v = *(const float4*)(basec + kq * 4);
      a0 = fmaf(v.x, WembL[(32 + kq * 4 + 0) * 32 + jj], a0);
      a1 = fmaf(v.y, WembL[(32 + kq * 4 + 1) * 32 + jj], a1);
      a2 = fmaf(v.z, WembL[(32 + kq * 4 + 2) * 32 + jj], a2);
      a3 = fmaf(v.w, WembL[(32 + kq * 4 + 3) * 32 + jj], a3);
    }
    smF[le * SF + i * 32 + jj] = (a0 + a1) + (a2 + a3);
  }

  f32x4 acc[4];
  ZERO_ACC();
  float sumsq = 0.f;

  // ---- GEMM1: 11 K-stages ----
  #pragma unroll 1
  for (int T = 0; T < 11; ++T) {
    __syncthreads();
    WPRE_STORE();
    {
      const float* fr = smF + j * SF;
      float xv[16];
      if (T < 8) {
        TRI16(T * 64 + w * 16);
      } else if (T == 8) {
        if (w == 0) {
          TRI16(512);
        } else {
          #pragma unroll
          for (int m = 0; m < 16; ++m) xv[m] = 0.f;
        }
      } else if (T == 9)  { XV_FROM_F4(gs); }
      else                { XV_FROM_F4(gc); }
      PACK_STORE_XV();
    }
    __syncthreads();
    WPRE_LOAD(wbf + (31 + T) * 4096);  // T=10 -> tile 41 (W2)
    MFMA_K64();
  }

  __syncthreads();
  red[w * 64 + j] = sumsq;
  #pragma unroll
  for (int nc = 0; nc < 4; ++nc) {
    const float bv = b1[nc * 16 + ll];
    #pragma unroll
    for (int r = 0; r < 4; ++r)
      Xl[(w * 16 + lh * 4 + r) * STX + nc * 16 + ll] = f2bf(fmaxf(acc[nc][r] + bv, 0.f));
  }
  WPRE_STORE();                      // W2
  ZERO_ACC();
  __syncthreads();
  WPRE_LOAD(wbf + 42 * 4096);        // GEMM3 nt=0
  if (t < 64) {
    const float ss = red[t] + red[64 + t] + red[128 + t] + red[192 + t];
    iFn[t] = 1.f / (sqrtf(ss) + 1.f);
  }

  MFMA_K64();                        // GEMM2
  #pragma unroll
  for (int nc = 0; nc < 4; ++nc) {
    const float bv = b2[nc * 16 + ll];
    #pragma unroll
    for (int r = 0; r < 4; ++r)
      Xl[(w * 16 + lh * 4 + r) * STX + nc * 16 + ll] = f2bf(fmaxf(acc[nc][r] + bv, 0.f));
  }

  float fcp[48];
  #pragma unroll
  for (int q = 0; q < 48; ++q) fcp[q] = 0.f;

  #pragma unroll 1
  for (int nt = 0; nt < 17; ++nt) {
    __syncthreads();
    WPRE_STORE();                    // tile 42+nt
    __syncthreads();
    if (nt < 16) WPRE_LOAD(wbf + (43 + nt) * 4096);
    ZERO_ACC();
    MFMA_K64();
    #pragma unroll
    for (int nc = 0; nc < 4; ++nc)
      #pragma unroll
      for (int r = 0; r < 4; ++r)
        C2h[(w * 16 + lh * 4 + r) * 65 + nc * 16 + ll] = f2bf(acc[nc][r]);
    const float bv = b3[nt * 64 + j];
    if (nt < 16) {
      const int a_ = nt * 2 + (j >> 5);
      #pragma unroll
      for (int m = 0; m < 16; ++m) {
        const float cv = (bf2f(C2h[(eb + m) * 65 + j]) + bv) * iFn[eb + m];
        const float* fr = smF + (eb + m) * SF;
        fcp[m * 3 + 0] = fmaf(fr[a_],      cv, fcp[m * 3 + 0]);
        fcp[m * 3 + 1] = fmaf(fr[32 + a_], cv, fcp[m * 3 + 1]);
        fcp[m * 3 + 2] = fmaf(fr[64 + a_], cv, fcp[m * 3 + 2]);
      }
    } else {
      #pragma unroll
      for (int m = 0; m < 16; ++m) {
        const int n_m = nbase + eb + m;
        const float cv = (bf2f(C2h[(eb + m) * 65 + j]) + bv) * iFn[eb + m];
        if (n_m < NN) os[n_m * 64 + j] = cv + s[n_m * 64 + j];
      }
    }
  }

  {
    const int b_ = j & 31;
    #pragma unroll
    for (int m = 0; m < 16; ++m) {
      const int n_m = nbase + eb + m;
      #pragma unroll
      for (int i = 0; i < 3; ++i) {
        float v = fcp[m * 3 + i];
        v += __shfl_xor(v, 32);
        if (j < 32 && n_m < NN)
          of[n_m * 96 + i * 32 + b_] = v + f[n_m * 96 + i * 32 + b_];
      }
    }
  }
}

extern "C" void kernel_launch(void* const* d_in, const int* in_sizes, int n_in,
                              void* d_out, int out_size, void* d_ws, size_t ws_size,
                              hipStream_t stream) {
  const float* f      = (const float*)d_in[0];
  const float* s      = (const float*)d_in[1];
  const float* edge_f = (const float*)d_in[2];
  const float* edge_s = (const float*)d_in[3];
  const float* Wemb1  = (const float*)d_in[4];
  const float* nW1 = (const float*)d_in[5];
  const float* nb1 = (const float*)d_in[6];
  const float* nW2 = (const float*)d_in[7];
  const float* nb2 = (const float*)d_in[8];
  const float* nW3 = (const float*)d_in[9];
  const float* nb3 = (const float*)d_in[10];
  const float* Wemb2 = (const float*)d_in[11];
  const float* sW1 = (const float*)d_in[12];
  const float* sb1 = (const float*)d_in[13];
  const float* sW2 = (const float*)d_in[14];
  const float* sb2 = (const float*)d_in[15];
  const float* sW3 = (const float*)d_in[16];
  const float* sb3 = (const float*)d_in[17];
  const int* eidx  = (const int*)d_in[18];

  float* of = (float*)d_out;               // [NN*96] ; aliases fc mean
  float* os = of + (size_t)NN * 96;        // [NN*64] ; aliases sc mean

  // ws: deg[NN] | cursor[NN] | start[NN] | sorted[NE] | wbf[59*4096] | tab[528]
  int* deg    = (int*)d_ws;
  int* cursor = deg + NN;
  int* start  = cursor + NN;
  int* sorted = start + NN;
  ushort* wbf = (ushort*)(sorted + NE);
  ushort* tab = wbf + 59 * 4096;

  hipMemsetAsync(deg, 0, (size_t)NN * 4, stream);
  hipMemsetAsync(d_out, 0, (size_t)NN * 160 * 4, stream);

  hipLaunchKernelGGL(sgnn_wconv, dim3((59 * 4096 + NTRI + 255) / 256), dim3(256),
                     0, stream, nW1, nW2, nW3, sW1, sW2, sW3, wbf, tab);
  hipLaunchKernelGGL(sgnn_hist, dim3((NE + 255) / 256), dim3(256), 0, stream,
                     eidx, deg);
  hipLaunchKernelGGL(sgnn_scan, dim3(1), dim3(1024), 0, stream, deg, cursor, start);
  hipLaunchKernelGGL(sgnn_scatter, dim3((NE + 255) / 256), dim3(256), 0, stream,
                     eidx, cursor, sorted);
  hipLaunchKernelGGL(sgnn_edge, dim3(NE / 64), dim3(256), 0, stream,
                     f, s, edge_f, edge_s, Wemb1, nb1, nb2, nb3,
                     wbf, tab, eidx, sorted, start, deg,
                     of /*fc_sum*/, os /*sc_sum*/);
  hipLaunchKernelGGL(sgnn_norm, dim3((NN * 160 + 255) / 256), dim3(256), 0, stream,
                     of, os, deg);
  hipLaunchKernelGGL(sgnn_node, dim3((NN + 63) / 64), dim3(256), 0, stream,
                     f, s, Wemb2, sb1, sb2, sb3,
                     wbf, tab, of /*fcm*/, os /*scm*/, of, os);
}

// Round 9
// 301.014 us; speedup vs baseline: 1.1548x; 1.0827x over previous
//
#include <hip/hip_runtime.h>
#include <math.h>

#define NN 10000
#define NE 80000
#define SF 97    // smF row stride (f32): stride%32==1 -> conflict-free per-lane rows
#define STX 72   // bf16 tile row stride (144B rows, 16B-aligned)
#define NTRI 528 // 32*33/2 unique Gram entries

typedef __attribute__((ext_vector_type(8))) __bf16 bf16x8;
typedef __attribute__((ext_vector_type(8))) short short8v;
typedef __attribute__((ext_vector_type(4))) float f32x4;
typedef __attribute__((ext_vector_type(4))) unsigned uint4v;

__device__ __forceinline__ ushort f2bf(float x) {
  union { float f; unsigned u; } v; v.f = x;
  unsigned r = v.u + 0x7FFFu + ((v.u >> 16) & 1u);
  return (ushort)(r >> 16);
}
__device__ __forceinline__ float bf2f(ushort u) {
  union { unsigned u; float f; } v; v.u = (unsigned)u << 16;
  return v.f;
}
__device__ __forceinline__ void tri_ab(int k, int& a, int& b) {
  int aa = 0, rem = k;
  while (rem >= 32 - aa) { rem -= 32 - aa; ++aa; }
  a = aa; b = aa + rem;
}

// ---- sort edges by e0 (verified R2/R3) ----
__global__ __launch_bounds__(256)
void sgnn_hist(const int* __restrict__ eidx, int* __restrict__ deg) {
  const int e = blockIdx.x * 256 + threadIdx.x;
  if (e < NE) atomicAdd(deg + eidx[e], 1);
}

__global__ __launch_bounds__(1024)
void sgnn_scan(const int* __restrict__ deg, int* __restrict__ cursor,
               int* __restrict__ start) {
  __shared__ int sm[1024];
  __shared__ int carry;
  const int t = threadIdx.x;
  if (t == 0) carry = 0;
  __syncthreads();
  for (int base = 0; base < NN; base += 1024) {
    const int i = base + t;
    const int v = (i < NN) ? deg[i] : 0;
    sm[t] = v;
    __syncthreads();
    #pragma unroll
    for (int d = 1; d < 1024; d <<= 1) {
      const int add = (t >= d) ? sm[t - d] : 0;
      __syncthreads();
      sm[t] += add;
      __syncthreads();
    }
    const int excl = carry + sm[t] - v;
    if (i < NN) { cursor[i] = excl; start[i] = excl; }
    __syncthreads();
    if (t == 1023) carry += sm[1023];
    __syncthreads();
  }
}

__global__ __launch_bounds__(256)
void sgnn_scatter(const int* __restrict__ eidx, int* __restrict__ cursor,
                  int* __restrict__ sorted) {
  const int e = blockIdx.x * 256 + threadIdx.x;
  if (e < NE) {
    const int p = atomicAdd(cursor + eidx[e], 1);
    sorted[p] = e;
  }
}

// ---- weight convert (verified R4): f32 -> blocked bf16, W1 K-folded symmetric ----
__global__ __launch_bounds__(256)
void sgnn_wconv(const float* __restrict__ nW1, const float* __restrict__ nW2,
                const float* __restrict__ nW3, const float* __restrict__ sW1,
                const float* __restrict__ sW2, const float* __restrict__ sW3,
                ushort* __restrict__ wout, ushort* __restrict__ tab) {
  const int gid = blockIdx.x * 256 + threadIdx.x;
  if (gid >= 59 * 4096) {
    const int k = gid - 59 * 4096;
    if (k < NTRI) {
      int a, b; tri_ab(k, a, b);
      tab[k] = (ushort)(a | (b << 8) | ((a != b) ? 0x8000 : 0));
    }
    return;
  }
  const int tile = gid >> 12, idx = gid & 4095;
  const int c = idx >> 6, k = idx & 63;
  float v = 0.f;
  if (tile < 12) {
    const int T = tile;
    if (T < 8 || (T == 8 && k < 16)) {
      const int ktri = T * 64 + k;
      if (ktri < NTRI) {
        int a, b; tri_ab(ktri, a, b);
        v = nW1[(a * 32 + b) * 64 + c];
        if (a != b) v += nW1[(b * 32 + a) * 64 + c];
      }
    } else if (T == 8) { if (k < 20) v = nW1[(1216 + (k - 16)) * 64 + c]; }
    else if (T == 9)   v = nW1[(1024 + k) * 64 + c];
    else if (T == 10)  v = nW1[(1088 + k) * 64 + c];
    else               v = nW1[(1152 + k) * 64 + c];
  } else if (tile == 12) v = nW2[k * 64 + c];
  else if (tile < 30)    v = nW3[k * 1088 + (tile - 13) * 64 + c];
  else if (tile < 41) {
    const int T = tile - 30;
    if (T < 8 || (T == 8 && k < 16)) {
      const int ktri = T * 64 + k;
      if (ktri < NTRI) {
        int a, b; tri_ab(ktri, a, b);
        v = sW1[(a * 32 + b) * 64 + c];
        if (a != b) v += sW1[(b * 32 + a) * 64 + c];
      }
    } else if (T == 9) v = sW1[(1024 + k) * 64 + c];
    else if (T == 10)  v = sW1[(1088 + k) * 64 + c];
  } else if (tile == 41) v = sW2[k * 64 + c];
  else                   v = sW3[k * 1088 + (tile - 42) * 64 + c];
  wout[gid] = f2bf(v);
}

// direct global->LDS W-tile stage (short-lived temps, spill-free)
#define STAGE_W(srcbase) do { const ushort* _s = (srcbase);                      \
  _Pragma("unroll") for (int rr = 0; rr < 2; ++rr) {                             \
    const int idx_ = t + 256 * rr; const int c_ = idx_ >> 3, ko_ = idx_ & 7;     \
    *(short8v*)&Wl[c_ * STX + ko_ * 8] = *(const short8v*)&_s[c_ * 64 + ko_ * 8];\
  } } while (0)

// W-tile prefetch (GEMM1 only): global -> regs (early), regs -> LDS (late)
#define WPRE_LOAD(srcbase) do { const ushort* _s = (srcbase);                    \
  wpre0 = *(const short8v*)&_s[(t >> 3) * 64 + (t & 7) * 8];                     \
  wpre1 = *(const short8v*)&_s[(32 + (t >> 3)) * 64 + (t & 7) * 8]; } while (0)

#define WPRE_STORE() do {                                                        \
  *(short8v*)&Wl[(t >> 3) * STX + (t & 7) * 8] = wpre0;                          \
  *(short8v*)&Wl[(32 + (t >> 3)) * STX + (t & 7) * 8] = wpre1; } while (0)

#define MFMA_K64() do {                                                          \
  _Pragma("unroll") for (int kb = 0; kb < 2; ++kb) {                             \
    const bf16x8 af_ = *(const bf16x8*)&Xl[(w * 16 + ll) * STX + kb * 32 + lh * 8]; \
    acc[0] = __builtin_amdgcn_mfma_f32_16x16x32_bf16(af_,                        \
        *(const bf16x8*)&Wl[(     ll) * STX + kb * 32 + lh * 8], acc[0], 0, 0, 0); \
    acc[1] = __builtin_amdgcn_mfma_f32_16x16x32_bf16(af_,                        \
        *(const bf16x8*)&Wl[(16 + ll) * STX + kb * 32 + lh * 8], acc[1], 0, 0, 0); \
    acc[2] = __builtin_amdgcn_mfma_f32_16x16x32_bf16(af_,                        \
        *(const bf16x8*)&Wl[(32 + ll) * STX + kb * 32 + lh * 8], acc[2], 0, 0, 0); \
    acc[3] = __builtin_amdgcn_mfma_f32_16x16x32_bf16(af_,                        \
        *(const bf16x8*)&Wl[(48 + ll) * STX + kb * 32 + lh * 8], acc[3], 0, 0, 0); \
  } } while (0)

#define ZERO_ACC() do { _Pragma("unroll") for (int q = 0; q < 4; ++q)            \
    acc[q] = (f32x4){0.f, 0.f, 0.f, 0.f}; } while (0)

// pack xv[16] (f32) -> 16 bf16, store as 2x b128 at Xl[row j, col w*16]
#define PACK_STORE_XV() do {                                                     \
  unsigned pk[8];                                                                \
  _Pragma("unroll") for (int q = 0; q < 8; ++q)                                  \
    pk[q] = (unsigned)f2bf(xv[2 * q]) | ((unsigned)f2bf(xv[2 * q + 1]) << 16);   \
  *(uint4v*)&Xl[j * STX + w * 16]     = (uint4v){pk[0], pk[1], pk[2], pk[3]};    \
  *(uint4v*)&Xl[j * STX + w * 16 + 8] = (uint4v){pk[4], pk[5], pk[6], pk[7]};    \
} while (0)

// tri staging for 16 contiguous k starting at kt; fa cached across runs
#define TRI16(kt) do {                                                           \
  int prev_a = -1; float fa0 = 0.f, fa1 = 0.f, fa2 = 0.f;                        \
  _Pragma("unroll") for (int m = 0; m < 16; ++m) {                               \
    const int tb = tabL[(kt) + m];                                               \
    const int a_ = tb & 31, b_ = (tb >> 8) & 31;                                 \
    if (a_ != prev_a) { fa0 = fr[a_]; fa1 = fr[32 + a_]; fa2 = fr[64 + a_];      \
                        prev_a = a_; }                                           \
    const float v = fmaf(fa0, fr[b_],                                            \
        fmaf(fa1, fr[32 + b_], fa2 * fr[64 + b_]));                              \
    const float wsel = (tb & 0x8000) ? 2.f : 1.f;                                \
    sumsq = fmaf(v * wsel, v, sumsq);                                            \
    xv[m] = v;                                                                   \
  } } while (0)

// inline 16-float gather (short-lived; no hoisting -> no spill)
#define XV_LOAD16(p) do { const float* _p = (p);                                 \
  _Pragma("unroll") for (int q = 0; q < 4; ++q) {                                \
    const float4 v4 = *(const float4*)(_p + 4 * q);                              \
    xv[4 * q + 0] = v4.x; xv[4 * q + 1] = v4.y;                                  \
    xv[4 * q + 2] = v4.z; xv[4 * q + 3] = v4.w; } } while (0)

// LDS carve (53152 B -> 3 blocks/CU)
#define LDS_BYTES 53152

__global__ __launch_bounds__(256, 2)
void sgnn_edge(const float* __restrict__ f, const float* __restrict__ s,
               const float* __restrict__ edge_f, const float* __restrict__ edge_s,
               const float* __restrict__ Wemb,
               const float* __restrict__ b1, const float* __restrict__ b2,
               const float* __restrict__ b3,
               const ushort* __restrict__ wbf, const ushort* __restrict__ tab_g,
               const int* __restrict__ eidx, const int* __restrict__ sorted,
               const int* __restrict__ start_g, const int* __restrict__ deg_g,
               float* __restrict__ fc_sum, float* __restrict__ sc_sum) {
  __shared__ __align__(16) char sbuf[LDS_BYTES];
  float*  smF  = (float*)sbuf;
  ushort* Xl   = (ushort*)(sbuf + 24832);
  ushort* Wl   = (ushort*)(sbuf + 34048);
  float*  R1f  = (float*)(sbuf + 43264);   // WembL(embed) / red(postG1)
  ushort* C2h  = (ushort*)(sbuf + 43264);  // bf16 [64][65] (G3)
  ushort* tabL = (ushort*)(sbuf + 51584);
  float*  iFn  = (float*)(sbuf + 51584);   // overlays tab after GEMM1
  int*    es_s = (int*)(sbuf + 52640);
  ushort* e0s  = (ushort*)(sbuf + 52896);
  ushort* e1s  = (ushort*)(sbuf + 53024);
  // flush-phase overlays on dead Xl region:
  float*  fcpart = (float*)(sbuf + 24832);          // [8][96]
  float*  scpart = (float*)(sbuf + 24832 + 3072);   // [8][64]
  int*    snode  = (int*)(sbuf + 24832 + 5120);     // [8]
  int*    sst    = (int*)(sbuf + 24832 + 5152);     // [8]
  int*    sdg    = (int*)(sbuf + 24832 + 5184);     // [8]

  const int t = threadIdx.x, j = t & 63, w = t >> 6, eb = w * 16;
  const int lh = j >> 4, ll = j & 15;
  const int bid = blockIdx.x;
  float* WembL = R1f;
  float* red   = R1f;
  short8v wpre0, wpre1;

  if (t < 64) {
    const int e = sorted[bid * 64 + t];
    es_s[t] = e;
    e0s[t] = (ushort)eidx[e];
    e1s[t] = (ushort)eidx[NE + e];
  }
  for (int idx = t; idx < NTRI; idx += 256) tabL[idx] = tab_g[idx];
  for (int idx = t; idx < 65 * 32; idx += 256) WembL[idx] = Wemb[idx];
  __syncthreads();

  // per-row node extent (lane m<16 holds row eb+m's start/deg)
  int str = 0, dgr = 0;
  if (j < 16) {
    const int n_ = e0s[eb + j];
    str = start_g[n_];
    dgr = deg_g[n_];
  }
  WPRE_LOAD(wbf + 0);   // W1 tile 0, hides under embed

  // ---- embed (f32): WembL broadcast reads; 4 accums break the fma chain ----
  #pragma unroll 1
  for (int r = 0; r < 24; ++r) {
    const int out = t + 256 * r;
    const int jj = out & 31;
    const int i = (out >> 5) % 3;
    const int le = out / 96;
    const float* base0 = f + e0s[le] * 96 + i * 32;
    const float* base1 = f + e1s[le] * 96 + i * 32;
    float a0 = 0.f, a1 = 0.f, a2 = 0.f, a3 = 0.f;
    #pragma unroll
    for (int kq = 0; kq < 8; ++kq) {
      const float4 v = *(const float4*)(base0 + kq * 4);
      a0 = fmaf(v.x, WembL[(kq * 4 + 0) * 32 + jj], a0);
      a1 = fmaf(v.y, WembL[(kq * 4 + 1) * 32 + jj], a1);
      a2 = fmaf(v.z, WembL[(kq * 4 + 2) * 32 + jj], a2);
      a3 = fmaf(v.w, WembL[(kq * 4 + 3) * 32 + jj], a3);
    }
    #pragma unroll
    for (int kq = 0; kq < 8; ++kq) {
      const float4 v = *(const float4*)(base1 + kq * 4);
      a0 = fmaf(v.x, WembL[(32 + kq * 4 + 0) * 32 + jj], a0);
      a1 = fmaf(v.y, WembL[(32 + kq * 4 + 1) * 32 + jj], a1);
      a2 = fmaf(v.z, WembL[(32 + kq * 4 + 2) * 32 + jj], a2);
      a3 = fmaf(v.w, WembL[(32 + kq * 4 + 3) * 32 + jj], a3);
    }
    a0 = fmaf(edge_f[es_s[le] * 3 + i], WembL[64 * 32 + jj], a0);
    smF[le * SF + i * 32 + jj] = (a0 + a1) + (a2 + a3);
  }

  f32x4 acc[4];
  ZERO_ACC();
  float sumsq = 0.f;

  // ---- GEMM1: 12 K-stages; W(T) via reg-prefetch, X inline-staged ----
  #pragma unroll 1
  for (int T = 0; T < 12; ++T) {
    __syncthreads();                 // prior MFMA done reading Xl/Wl
    WPRE_STORE();                    // W(T) regs -> Wl
    {
      const float* fr = smF + j * SF;
      float xv[16];
      if (T < 8) {
        TRI16(T * 64 + w * 16);
      } else if (T == 8) {
        if (w == 0) {
          TRI16(512);
        } else if (w == 1) {
          const float4 v4 = *(const float4*)(edge_s + es_s[j] * 68 + 64);
          xv[0] = v4.x; xv[1] = v4.y; xv[2] = v4.z; xv[3] = v4.w;
          #pragma unroll
          for (int m = 4; m < 16; ++m) xv[m] = 0.f;
        } else {
          #pragma unroll
          for (int m = 0; m < 16; ++m) xv[m] = 0.f;
        }
      } else if (T == 9)  { XV_LOAD16(s + e0s[j] * 64 + w * 16); }
      else if (T == 10)   { XV_LOAD16(s + e1s[j] * 64 + w * 16); }
      else                { XV_LOAD16(edge_s + es_s[j] * 68 + w * 16); }
      PACK_STORE_XV();
    }
    __syncthreads();
    WPRE_LOAD(wbf + (T + 1) * 4096); // T=11 -> tile 12 (W2); hides under MFMA
    MFMA_K64();
  }

  // ---- h1 epilogue + Fn reduce; W2 arrives via last prefetch ----
  __syncthreads();
  red[w * 64 + j] = sumsq;
  #pragma unroll
  for (int nc = 0; nc < 4; ++nc) {
    const float bv = b1[nc * 16 + ll];
    #pragma unroll
    for (int r = 0; r < 4; ++r)
      Xl[(w * 16 + lh * 4 + r) * STX + nc * 16 + ll] = f2bf(fmaxf(acc[nc][r] + bv, 0.f));
  }
  WPRE_STORE();                      // W2 -> Wl (wpre dead afterwards)
  ZERO_ACC();
  __syncthreads();
  if (t < 64) {
    const float ss = red[t] + red[64 + t] + red[128 + t] + red[192 + t];
    iFn[t] = 1.f / (sqrtf(ss) + 1.f);
  }

  // ---- GEMM2 (h1 strip is wave-local) ----
  MFMA_K64();
  #pragma unroll
  for (int nc = 0; nc < 4; ++nc) {
    const float bv = b2[nc * 16 + ll];
    #pragma unroll
    for (int r = 0; r < 4; ++r)
      Xl[(w * 16 + lh * 4 + r) * STX + nc * 16 + ll] = f2bf(fmaxf(acc[nc][r] + bv, 0.f));
  }

  // ---- GEMM3 (17 n-tiles) + fused consume; direct stage (spill-free) ----
  float fcp[48];
  #pragma unroll
  for (int q = 0; q < 48; ++q) fcp[q] = 0.f;
  float csv[16];

  #pragma unroll 1
  for (int nt = 0; nt < 17; ++nt) {
    __syncthreads();                 // all waves done reading Wl
    STAGE_W(wbf + (13 + nt) * 4096);
    __syncthreads();
    ZERO_ACC();
    MFMA_K64();
    #pragma unroll
    for (int nc = 0; nc < 4; ++nc)
      #pragma unroll
      for (int r = 0; r < 4; ++r)
        C2h[(w * 16 + lh * 4 + r) * 65 + nc * 16 + ll] = f2bf(acc[nc][r]);
    // wave-private rows: no barrier needed before consume
    const float bv = b3[nt * 64 + j];
    if (nt < 16) {
      const int a_ = nt * 2 + (j >> 5);
      #pragma unroll
      for (int m = 0; m < 16; ++m) {
        const float cv = (bf2f(C2h[(eb + m) * 65 + j]) + bv) * iFn[eb + m];
        const float* fr = smF + (eb + m) * SF;
        fcp[m * 3 + 0] = fmaf(fr[a_],      cv, fcp[m * 3 + 0]);
        fcp[m * 3 + 1] = fmaf(fr[32 + a_], cv, fcp[m * 3 + 1]);
        fcp[m * 3 + 2] = fmaf(fr[64 + a_], cv, fcp[m * 3 + 2]);
      }
    } else {
      #pragma unroll
      for (int m = 0; m < 16; ++m)
        csv[m] = (bf2f(C2h[(eb + m) * 65 + j]) + bv) * iFn[eb + m];
    }
  }

  // ---- flush (verified R5): complete-run stores, partials via LDS merge ----
  __syncthreads();
  if (t < 8) snode[t] = -1;
  __syncthreads();

  {
    float r0 = 0.f, r1 = 0.f, r2 = 0.f, rs = 0.f;
    int runlen = 0;
    const int gwb = bid * 64 + eb;
    #pragma unroll
    for (int m = 0; m < 16; ++m) {
      float v0 = fcp[m * 3 + 0]; v0 += __shfl_xor(v0, 32);
      float v1 = fcp[m * 3 + 1]; v1 += __shfl_xor(v1, 32);
      float v2 = fcp[m * 3 + 2]; v2 += __shfl_xor(v2, 32);
      r0 += v0; r1 += v1; r2 += v2; rs += csv[m];
      ++runlen;
      const int n = e0s[eb + m];
      if (m == 15 || e0s[eb + m + 1] != n) {
        const int st = __shfl(str, m);
        const int dg = __shfl(dgr, m);
        const int g1v = gwb + m, g0v = g1v - runlen + 1;
        if (g0v == st && runlen == dg) {
          if (j < 32) {
            fc_sum[n * 96 + j]      = r0;
            fc_sum[n * 96 + 32 + j] = r1;
            fc_sum[n * 96 + 64 + j] = r2;
          }
          sc_sum[n * 64 + j] = rs;
        } else {
          const int slot = (g0v == gwb) ? 2 * w : 2 * w + 1;
          if (j < 32) {
            fcpart[slot * 96 + j]      = r0;
            fcpart[slot * 96 + 32 + j] = r1;
            fcpart[slot * 96 + 64 + j] = r2;
          }
          scpart[slot * 64 + j] = rs;
          if (j == 0) { snode[slot] = n; sst[slot] = st; sdg[slot] = dg; }
        }
        r0 = r1 = r2 = rs = 0.f; runlen = 0;
      }
    }
  }
  __syncthreads();

  if (t < 160) {
    const int ch = t;
    int prevn = -1;
    #pragma unroll 1
    for (int ss = 0; ss < 8; ++ss) {
      const int n = snode[ss];
      if (n < 0) { continue; }
      if (n != prevn) {
        float v = (ch < 96) ? fcpart[ss * 96 + ch] : scpart[ss * 64 + (ch - 96)];
        #pragma unroll 1
        for (int k2 = ss + 1; k2 < 8; ++k2) {
          if (snode[k2] == n)
            v += (ch < 96) ? fcpart[k2 * 96 + ch] : scpart[k2 * 64 + (ch - 96)];
          else if (snode[k2] >= 0) break;
        }
        const bool cib = (sst[ss] >= bid * 64) && (sst[ss] + sdg[ss] <= bid * 64 + 64);
        float* dst = (ch < 96) ? (fc_sum + n * 96 + ch) : (sc_sum + n * 64 + (ch - 96));
        if (cib) *dst = v; else atomicAdd(dst, v);
      }
      prevn = n;
    }
  }
}

// sums -> means
__global__ __launch_bounds__(256)
void sgnn_norm(float* __restrict__ fcm, float* __restrict__ scm,
               const int* __restrict__ deg) {
  const int idx = blockIdx.x * 256 + threadIdx.x;
  if (idx >= NN * 160) return;
  const int n = idx / 160, c = idx % 160;
  const float ic = 1.f / fmaxf((float)deg[n], 1.f);
  if (c < 96) fcm[n * 96 + c] *= ic;
  else        scm[n * 64 + (c - 96)] *= ic;
}

__global__ __launch_bounds__(256, 2)
void sgnn_node(const float* __restrict__ f, const float* __restrict__ s,
               const float* __restrict__ Wemb,
               const float* __restrict__ b1, const float* __restrict__ b2,
               const float* __restrict__ b3,
               const ushort* __restrict__ wbf, const ushort* __restrict__ tab_g,
               const float* __restrict__ fcm, const float* __restrict__ scm,
               float* __restrict__ of, float* __restrict__ os) {
  __shared__ __align__(16) char sbuf[LDS_BYTES];
  float*  smF  = (float*)sbuf;
  ushort* Xl   = (ushort*)(sbuf + 24832);
  ushort* Wl   = (ushort*)(sbuf + 34048);
  float*  R1f  = (float*)(sbuf + 43264);
  ushort* C2h  = (ushort*)(sbuf + 43264);
  ushort* tabL = (ushort*)(sbuf + 51584);
  float*  iFn  = (float*)(sbuf + 51584);

  const int t = threadIdx.x, j = t & 63, w = t >> 6, eb = w * 16;
  const int lh = j >> 4, ll = j & 15;
  const int nbase = blockIdx.x * 64;
  float* WembL = R1f;
  float* red   = R1f;
  short8v wpre0, wpre1;

  for (int idx = t; idx < NTRI; idx += 256) tabL[idx] = tab_g[idx];
  for (int idx = t; idx < 64 * 32; idx += 256) WembL[idx] = Wemb[idx];
  WPRE_LOAD(wbf + 30 * 4096);
  __syncthreads();

  // ---- embed: tf = concat(f, f_c_mean) @ Wemb2 ----
  #pragma unroll 1
  for (int r = 0; r < 24; ++r) {
    const int out = t + 256 * r;
    const int jj = out & 31;
    const int i = (out >> 5) % 3;
    const int le = out / 96;
    const int nc = min(nbase + le, NN - 1);
    const float* base0 = f + nc * 96 + i * 32;
    const float* basec = fcm + nc * 96 + i * 32;
    float a0 = 0.f, a1 = 0.f, a2 = 0.f, a3 = 0.f;
    #pragma unroll
    for (int kq = 0; kq < 8; ++kq) {
      const float4 v = *(const float4*)(base0 + kq * 4);
      a0 = fmaf(v.x, WembL[(kq * 4 + 0) * 32 + jj], a0);
      a1 = fmaf(v.y, WembL[(kq * 4 + 1) * 32 + jj], a1);
      a2 = fmaf(v.z, WembL[(kq * 4 + 2) * 32 + jj], a2);
      a3 = fmaf(v.w, WembL[(kq * 4 + 3) * 32 + jj], a3);
    }
    #pragma unroll
    for (int kq = 0; kq < 8; ++kq) {
      const float4 v = *(const float4*)(basec + kq * 4);
      a0 = fmaf(v.x, WembL[(32 + kq * 4 + 0) * 32 + jj], a0);
      a1 = fmaf(v.y, WembL[(32 + kq * 4 + 1) * 32 + jj], a1);
      a2 = fmaf(v.z, WembL[(32 + kq * 4 + 2) * 32 + jj], a2);
      a3 = fmaf(v.w, WembL[(32 + kq * 4 + 3) * 32 + jj], a3);
    }
    smF[le * SF + i * 32 + jj] = (a0 + a1) + (a2 + a3);
  }

  f32x4 acc[4];
  ZERO_ACC();
  float sumsq = 0.f;

  // ---- GEMM1: 11 K-stages ----
  #pragma unroll 1
  for (int T = 0; T < 11; ++T) {
    __syncthreads();
    WPRE_STORE();
    {
      const float* fr = smF + j * SF;
      float xv[16];
      if (T < 8) {
        TRI16(T * 64 + w * 16);
      } else if (T == 8) {
        if (w == 0) {
          TRI16(512);
        } else {
          #pragma unroll
          for (int m = 0; m < 16; ++m) xv[m] = 0.f;
        }
      } else if (T == 9) {
        XV_LOAD16(s + min(nbase + j, NN - 1) * 64 + w * 16);
      } else {
        XV_LOAD16(scm + min(nbase + j, NN - 1) * 64 + w * 16);
      }
      PACK_STORE_XV();
    }
    __syncthreads();
    WPRE_LOAD(wbf + (31 + T) * 4096);  // T=10 -> tile 41 (W2)
    MFMA_K64();
  }

  __syncthreads();
  red[w * 64 + j] = sumsq;
  #pragma unroll
  for (int nc = 0; nc < 4; ++nc) {
    const float bv = b1[nc * 16 + ll];
    #pragma unroll
    for (int r = 0; r < 4; ++r)
      Xl[(w * 16 + lh * 4 + r) * STX + nc * 16 + ll] = f2bf(fmaxf(acc[nc][r] + bv, 0.f));
  }
  WPRE_STORE();                      // W2
  ZERO_ACC();
  __syncthreads();
  if (t < 64) {
    const float ss = red[t] + red[64 + t] + red[128 + t] + red[192 + t];
    iFn[t] = 1.f / (sqrtf(ss) + 1.f);
  }

  MFMA_K64();                        // GEMM2
  #pragma unroll
  for (int nc = 0; nc < 4; ++nc) {
    const float bv = b2[nc * 16 + ll];
    #pragma unroll
    for (int r = 0; r < 4; ++r)
      Xl[(w * 16 + lh * 4 + r) * STX + nc * 16 + ll] = f2bf(fmaxf(acc[nc][r] + bv, 0.f));
  }

  float fcp[48];
  #pragma unroll
  for (int q = 0; q < 48; ++q) fcp[q] = 0.f;

  #pragma unroll 1
  for (int nt = 0; nt < 17; ++nt) {
    __syncthreads();
    STAGE_W(wbf + (42 + nt) * 4096);
    __syncthreads();
    ZERO_ACC();
    MFMA_K64();
    #pragma unroll
    for (int nc = 0; nc < 4; ++nc)
      #pragma unroll
      for (int r = 0; r < 4; ++r)
        C2h[(w * 16 + lh * 4 + r) * 65 + nc * 16 + ll] = f2bf(acc[nc][r]);
    const float bv = b3[nt * 64 + j];
    if (nt < 16) {
      const int a_ = nt * 2 + (j >> 5);
      #pragma unroll
      for (int m = 0; m < 16; ++m) {
        const float cv = (bf2f(C2h[(eb + m) * 65 + j]) + bv) * iFn[eb + m];
        const float* fr = smF + (eb + m) * SF;
        fcp[m * 3 + 0] = fmaf(fr[a_],      cv, fcp[m * 3 + 0]);
        fcp[m * 3 + 1] = fmaf(fr[32 + a_], cv, fcp[m * 3 + 1]);
        fcp[m * 3 + 2] = fmaf(fr[64 + a_], cv, fcp[m * 3 + 2]);
      }
    } else {
      #pragma unroll
      for (int m = 0; m < 16; ++m) {
        const int n_m = nbase + eb + m;
        const float cv = (bf2f(C2h[(eb + m) * 65 + j]) + bv) * iFn[eb + m];
        if (n_m < NN) os[n_m * 64 + j] = cv + s[n_m * 64 + j];
      }
    }
  }

  {
    const int b_ = j & 31;
    #pragma unroll
    for (int m = 0; m < 16; ++m) {
      const int n_m = nbase + eb + m;
      #pragma unroll
      for (int i = 0; i < 3; ++i) {
        float v = fcp[m * 3 + i];
        v += __shfl_xor(v, 32);
        if (j < 32 && n_m < NN)
          of[n_m * 96 + i * 32 + b_] = v + f[n_m * 96 + i * 32 + b_];
      }
    }
  }
}

extern "C" void kernel_launch(void* const* d_in, const int* in_sizes, int n_in,
                              void* d_out, int out_size, void* d_ws, size_t ws_size,
                              hipStream_t stream) {
  const float* f      = (const float*)d_in[0];
  const float* s      = (const float*)d_in[1];
  const float* edge_f = (const float*)d_in[2];
  const float* edge_s = (const float*)d_in[3];
  const float* Wemb1  = (const float*)d_in[4];
  const float* nW1 = (const float*)d_in[5];
  const float* nb1 = (const float*)d_in[6];
  const float* nW2 = (const float*)d_in[7];
  const float* nb2 = (const float*)d_in[8];
  const float* nW3 = (const float*)d_in[9];
  const float* nb3 = (const float*)d_in[10];
  const float* Wemb2 = (const float*)d_in[11];
  const float* sW1 = (const float*)d_in[12];
  const float* sb1 = (const float*)d_in[13];
  const float* sW2 = (const float*)d_in[14];
  const float* sb2 = (const float*)d_in[15];
  const float* sW3 = (const float*)d_in[16];
  const float* sb3 = (const float*)d_in[17];
  const int* eidx  = (const int*)d_in[18];

  float* of = (float*)d_out;               // [NN*96] ; aliases fc mean
  float* os = of + (size_t)NN * 96;        // [NN*64] ; aliases sc mean

  // ws: deg[NN] | cursor[NN] | start[NN] | sorted[NE] | wbf[59*4096] | tab[528]
  int* deg    = (int*)d_ws;
  int* cursor = deg + NN;
  int* start  = cursor + NN;
  int* sorted = start + NN;
  ushort* wbf = (ushort*)(sorted + NE);
  ushort* tab = wbf + 59 * 4096;

  hipMemsetAsync(deg, 0, (size_t)NN * 4, stream);
  hipMemsetAsync(d_out, 0, (size_t)NN * 160 * 4, stream);

  hipLaunchKernelGGL(sgnn_wconv, dim3((59 * 4096 + NTRI + 255) / 256), dim3(256),
                     0, stream, nW1, nW2, nW3, sW1, sW2, sW3, wbf, tab);
  hipLaunchKernelGGL(sgnn_hist, dim3((NE + 255) / 256), dim3(256), 0, stream,
                     eidx, deg);
  hipLaunchKernelGGL(sgnn_scan, dim3(1), dim3(1024), 0, stream, deg, cursor, start);
  hipLaunchKernelGGL(sgnn_scatter, dim3((NE + 255) / 256), dim3(256), 0, stream,
                     eidx, cursor, sorted);
  hipLaunchKernelGGL(sgnn_edge, dim3(NE / 64), dim3(256), 0, stream,
                     f, s, edge_f, edge_s, Wemb1, nb1, nb2, nb3,
                     wbf, tab, eidx, sorted, start, deg,
                     of /*fc_sum*/, os /*sc_sum*/);
  hipLaunchKernelGGL(sgnn_norm, dim3((NN * 160 + 255) / 256), dim3(256), 0, stream,
                     of, os, deg);
  hipLaunchKernelGGL(sgnn_node, dim3((NN + 63) / 64), dim3(256), 0, stream,
                     f, s, Wemb2, sb1, sb2, sb3,
                     wbf, tab, of /*fcm*/, os /*scm*/, of, os);
}

// Round 10
// 238.488 us; speedup vs baseline: 1.4575x; 1.2622x over previous
//
#include <hip/hip_runtime.h>
#include <math.h>

#define NN 10000
#define NE 80000
#define SF 97    // smF row stride (f32): stride%32==1 -> conflict-free per-lane rows
#define STX 72   // bf16 tile row stride (144B rows, 16B-aligned)
#define NTRI 528 // 32*33/2 unique Gram entries
#define SAE 104  // edge embed A stride (bf16), 208B: rows alias 8 apart -> 2-way only
#define SAN 72   // node embed A stride (bf16)

typedef __attribute__((ext_vector_type(8))) __bf16 bf16x8;
typedef __attribute__((ext_vector_type(8))) short short8v;
typedef __attribute__((ext_vector_type(4))) float f32x4;
typedef __attribute__((ext_vector_type(4))) unsigned uint4v;

__device__ __forceinline__ ushort f2bf(float x) {
  union { float f; unsigned u; } v; v.f = x;
  unsigned r = v.u + 0x7FFFu + ((v.u >> 16) & 1u);
  return (ushort)(r >> 16);
}
__device__ __forceinline__ float bf2f(ushort u) {
  union { unsigned u; float f; } v; v.u = (unsigned)u << 16;
  return v.f;
}
__device__ __forceinline__ void tri_ab(int k, int& a, int& b) {
  int aa = 0, rem = k;
  while (rem >= 32 - aa) { rem -= 32 - aa; ++aa; }
  a = aa; b = aa + rem;
}

// ---- sort edges by e0 (verified R2/R3) ----
__global__ __launch_bounds__(256)
void sgnn_hist(const int* __restrict__ eidx, int* __restrict__ deg) {
  const int e = blockIdx.x * 256 + threadIdx.x;
  if (e < NE) atomicAdd(deg + eidx[e], 1);
}

__global__ __launch_bounds__(1024)
void sgnn_scan(const int* __restrict__ deg, int* __restrict__ cursor,
               int* __restrict__ start) {
  __shared__ int sm[1024];
  __shared__ int carry;
  const int t = threadIdx.x;
  if (t == 0) carry = 0;
  __syncthreads();
  for (int base = 0; base < NN; base += 1024) {
    const int i = base + t;
    const int v = (i < NN) ? deg[i] : 0;
    sm[t] = v;
    __syncthreads();
    #pragma unroll
    for (int d = 1; d < 1024; d <<= 1) {
      const int add = (t >= d) ? sm[t - d] : 0;
      __syncthreads();
      sm[t] += add;
      __syncthreads();
    }
    const int excl = carry + sm[t] - v;
    if (i < NN) { cursor[i] = excl; start[i] = excl; }
    __syncthreads();
    if (t == 1023) carry += sm[1023];
    __syncthreads();
  }
}

__global__ __launch_bounds__(256)
void sgnn_scatter(const int* __restrict__ eidx, int* __restrict__ cursor,
                  int* __restrict__ sorted) {
  const int e = blockIdx.x * 256 + threadIdx.x;
  if (e < NE) {
    const int p = atomicAdd(cursor + eidx[e], 1);
    sorted[p] = e;
  }
}

// ---- weight convert: blocked bf16 tiles; +59: Wemb1^T [32][96], +60: Wemb2^T [32][64]
__global__ __launch_bounds__(256)
void sgnn_wconv(const float* __restrict__ nW1, const float* __restrict__ nW2,
                const float* __restrict__ nW3, const float* __restrict__ sW1,
                const float* __restrict__ sW2, const float* __restrict__ sW3,
                const float* __restrict__ Wemb1, const float* __restrict__ Wemb2,
                ushort* __restrict__ wout, ushort* __restrict__ tab) {
  const int gid = blockIdx.x * 256 + threadIdx.x;
  if (gid >= 61 * 4096) {
    const int k = gid - 61 * 4096;
    if (k < NTRI) {
      int a, b; tri_ab(k, a, b);
      tab[k] = (ushort)(a | (b << 8) | ((a != b) ? 0x8000 : 0));
    }
    return;
  }
  const int tile = gid >> 12, idx = gid & 4095;
  const int c = idx >> 6, k = idx & 63;
  float v = 0.f;
  if (tile < 12) {
    const int T = tile;
    if (T < 8 || (T == 8 && k < 16)) {
      const int ktri = T * 64 + k;
      if (ktri < NTRI) {
        int a, b; tri_ab(ktri, a, b);
        v = nW1[(a * 32 + b) * 64 + c];
        if (a != b) v += nW1[(b * 32 + a) * 64 + c];
      }
    } else if (T == 8) { if (k < 20) v = nW1[(1216 + (k - 16)) * 64 + c]; }
    else if (T == 9)   v = nW1[(1024 + k) * 64 + c];
    else if (T == 10)  v = nW1[(1088 + k) * 64 + c];
    else               v = nW1[(1152 + k) * 64 + c];
  } else if (tile == 12) v = nW2[k * 64 + c];
  else if (tile < 30)    v = nW3[k * 1088 + (tile - 13) * 64 + c];
  else if (tile < 41) {
    const int T = tile - 30;
    if (T < 8 || (T == 8 && k < 16)) {
      const int ktri = T * 64 + k;
      if (ktri < NTRI) {
        int a, b; tri_ab(ktri, a, b);
        v = sW1[(a * 32 + b) * 64 + c];
        if (a != b) v += sW1[(b * 32 + a) * 64 + c];
      }
    } else if (T == 9) v = sW1[(1024 + k) * 64 + c];
    else if (T == 10)  v = sW1[(1088 + k) * 64 + c];
  } else if (tile == 41) v = sW2[k * 64 + c];
  else if (tile < 59)    v = sW3[k * 1088 + (tile - 42) * 64 + c];
  else if (tile == 59) {
    const int col = idx / 96, kk = idx % 96;
    v = (col < 32 && kk < 65) ? Wemb1[kk * 32 + col] : 0.f;
  } else {
    const int col = idx >> 6;
    v = (col < 32) ? Wemb2[k * 32 + col] : 0.f;
  }
  wout[gid] = f2bf(v);
}

// direct global->LDS W-tile stage (short-lived temps, spill-free)
#define STAGE_W(srcbase) do { const ushort* _s = (srcbase);                      \
  _Pragma("unroll") for (int rr = 0; rr < 2; ++rr) {                             \
    const int idx_ = t + 256 * rr; const int c_ = idx_ >> 3, ko_ = idx_ & 7;     \
    *(short8v*)&Wl[c_ * STX + ko_ * 8] = *(const short8v*)&_s[c_ * 64 + ko_ * 8];\
  } } while (0)

// W-tile prefetch (GEMM1 only): global -> regs (early), regs -> LDS (late)
#define WPRE_LOAD(srcbase) do { const ushort* _s = (srcbase);                    \
  wpre0 = *(const short8v*)&_s[(t >> 3) * 64 + (t & 7) * 8];                     \
  wpre1 = *(const short8v*)&_s[(32 + (t >> 3)) * 64 + (t & 7) * 8]; } while (0)

#define WPRE_STORE() do {                                                        \
  *(short8v*)&Wl[(t >> 3) * STX + (t & 7) * 8] = wpre0;                          \
  *(short8v*)&Wl[(32 + (t >> 3)) * STX + (t & 7) * 8] = wpre1; } while (0)

#define MFMA_K64() do {                                                          \
  _Pragma("unroll") for (int kb = 0; kb < 2; ++kb) {                             \
    const bf16x8 af_ = *(const bf16x8*)&Xl[(w * 16 + ll) * STX + kb * 32 + lh * 8]; \
    acc[0] = __builtin_amdgcn_mfma_f32_16x16x32_bf16(af_,                        \
        *(const bf16x8*)&Wl[(     ll) * STX + kb * 32 + lh * 8], acc[0], 0, 0, 0); \
    acc[1] = __builtin_amdgcn_mfma_f32_16x16x32_bf16(af_,                        \
        *(const bf16x8*)&Wl[(16 + ll) * STX + kb * 32 + lh * 8], acc[1], 0, 0, 0); \
    acc[2] = __builtin_amdgcn_mfma_f32_16x16x32_bf16(af_,                        \
        *(const bf16x8*)&Wl[(32 + ll) * STX + kb * 32 + lh * 8], acc[2], 0, 0, 0); \
    acc[3] = __builtin_amdgcn_mfma_f32_16x16x32_bf16(af_,                        \
        *(const bf16x8*)&Wl[(48 + ll) * STX + kb * 32 + lh * 8], acc[3], 0, 0, 0); \
  } } while (0)

#define ZERO_ACC() do { _Pragma("unroll") for (int q = 0; q < 4; ++q)            \
    acc[q] = (f32x4){0.f, 0.f, 0.f, 0.f}; } while (0)

// pack xv[16] (f32) -> 16 bf16, store as 2x b128 at dst (element offset)
#define PACK_STORE16(dstp) do {                                                  \
  unsigned pk[8];                                                                \
  _Pragma("unroll") for (int q = 0; q < 8; ++q)                                  \
    pk[q] = (unsigned)f2bf(xv[2 * q]) | ((unsigned)f2bf(xv[2 * q + 1]) << 16);   \
  *(uint4v*)(dstp)       = (uint4v){pk[0], pk[1], pk[2], pk[3]};                 \
  *(uint4v*)((dstp) + 8) = (uint4v){pk[4], pk[5], pk[6], pk[7]};                 \
} while (0)

// tri staging for 16 contiguous k starting at kt; fa cached across runs
#define TRI16(kt) do {                                                           \
  int prev_a = -1; float fa0 = 0.f, fa1 = 0.f, fa2 = 0.f;                        \
  _Pragma("unroll") for (int m = 0; m < 16; ++m) {                               \
    const int tb = tabL[(kt) + m];                                               \
    const int a_ = tb & 31, b_ = (tb >> 8) & 31;                                 \
    if (a_ != prev_a) { fa0 = fr[a_]; fa1 = fr[32 + a_]; fa2 = fr[64 + a_];      \
                        prev_a = a_; }                                           \
    const float v = fmaf(fa0, fr[b_],                                            \
        fmaf(fa1, fr[32 + b_], fa2 * fr[64 + b_]));                              \
    const float wsel = (tb & 0x8000) ? 2.f : 1.f;                                \
    sumsq = fmaf(v * wsel, v, sumsq);                                            \
    xv[m] = v;                                                                   \
  } } while (0)

// inline 16-float gather (short-lived; no hoisting -> no spill)
#define XV_LOAD16(p) do { const float* _p = (p);                                 \
  _Pragma("unroll") for (int q = 0; q < 4; ++q) {                                \
    const float4 v4 = *(const float4*)(_p + 4 * q);                              \
    xv[4 * q + 0] = v4.x; xv[4 * q + 1] = v4.y;                                  \
    xv[4 * q + 2] = v4.z; xv[4 * q + 3] = v4.w; } } while (0)

// LDS carve (53152 B -> 3 blocks/CU)
#define LDS_BYTES 53152

__global__ __launch_bounds__(256, 2)
void sgnn_edge(const float* __restrict__ f, const float* __restrict__ s,
               const float* __restrict__ edge_f, const float* __restrict__ edge_s,
               const float* __restrict__ b1, const float* __restrict__ b2,
               const float* __restrict__ b3,
               const ushort* __restrict__ wbf, const ushort* __restrict__ tab_g,
               const int* __restrict__ eidx, const int* __restrict__ sorted,
               const int* __restrict__ start_g, const int* __restrict__ deg_g,
               float* __restrict__ fc_sum, float* __restrict__ sc_sum) {
  __shared__ __align__(16) char sbuf[LDS_BYTES];
  float*  smF  = (float*)sbuf;
  ushort* Xl   = (ushort*)(sbuf + 24832);
  ushort* Wl   = (ushort*)(sbuf + 34048);
  ushort* Aemb = (ushort*)(sbuf + 24832);  // embed A [96][SAE] spans Xl..C2h head
  float*  red  = (float*)(sbuf + 43264);
  ushort* C2h  = (ushort*)(sbuf + 43264);  // bf16 [64][65] (G3)
  ushort* tabL = (ushort*)(sbuf + 51584);
  float*  iFn  = (float*)(sbuf + 51584);   // overlays tab after GEMM1
  int*    es_s = (int*)(sbuf + 52640);
  ushort* e0s  = (ushort*)(sbuf + 52896);
  ushort* e1s  = (ushort*)(sbuf + 53024);
  // flush-phase overlays on dead Xl region:
  float*  fcpart = (float*)(sbuf + 24832);          // [8][96]
  float*  scpart = (float*)(sbuf + 24832 + 3072);   // [8][64]
  int*    snode  = (int*)(sbuf + 24832 + 5120);     // [8]
  int*    sst    = (int*)(sbuf + 24832 + 5152);     // [8]
  int*    sdg    = (int*)(sbuf + 24832 + 5184);     // [8]

  const int t = threadIdx.x, j = t & 63, w = t >> 6, eb = w * 16;
  const int lh = j >> 4, ll = j & 15;
  const int bid = blockIdx.x;
  const ushort* wembT = wbf + 59 * 4096;   // Wemb1^T [32 col][96 k] bf16
  short8v wpre0, wpre1;

  if (t < 64) {
    const int e = sorted[bid * 64 + t];
    es_s[t] = e;
    e0s[t] = (ushort)eidx[e];
    e1s[t] = (ushort)eidx[NE + e];
  }
  for (int idx = t; idx < NTRI; idx += 256) tabL[idx] = tab_g[idx];
  __syncthreads();

  // per-row node extent (lane m<16 holds row eb+m's start/deg)
  int str = 0, dgr = 0;
  if (j < 16) {
    const int n_ = e0s[eb + j];
    str = start_g[n_];
    dgr = deg_g[n_];
  }
  WPRE_LOAD(wbf + 0);   // W1 tile 0, hides under embed

  // ---- MFMA embed: smF = concat(f[e0],f[e1],edge_f) @ Wemb1, 2 halves ----
  #pragma unroll 1
  for (int h = 0; h < 2; ++h) {
    const int hb = h * 32;
    #pragma unroll 1
    for (int cc = t; cc < 576; cc += 256) {     // 96 rows x 6 k-segs
      const int row = cc / 6, seg = cc - row * 6;
      const int lel = (row * 43) >> 7, il = row - lel * 3;
      const int k0 = seg * 16;
      float xv[16];
      if (seg < 4) {
        const int nd = (seg < 2) ? (int)e0s[hb + lel] : (int)e1s[hb + lel];
        XV_LOAD16(f + nd * 96 + il * 32 + (seg & 1) * 16);
      } else if (seg == 4) {
        xv[0] = edge_f[es_s[hb + lel] * 3 + il];
        #pragma unroll
        for (int m = 1; m < 16; ++m) xv[m] = 0.f;
      } else {
        #pragma unroll
        for (int m = 0; m < 16; ++m) xv[m] = 0.f;
      }
      PACK_STORE16(&Aemb[row * SAE + k0]);
    }
    __syncthreads();
    #pragma unroll 1
    for (int job = w * 3; job < w * 3 + 3; ++job) {   // 12 jobs: 6 mt x 2 nt
      const int mt = job >> 1, nt = job & 1;
      f32x4 ac = (f32x4){0.f, 0.f, 0.f, 0.f};
      #pragma unroll
      for (int kb = 0; kb < 3; ++kb) {
        const bf16x8 av = *(const bf16x8*)&Aemb[(mt * 16 + ll) * SAE + kb * 32 + lh * 8];
        const bf16x8 bv = *(const bf16x8*)&wembT[(nt * 16 + ll) * 96 + kb * 32 + lh * 8];
        ac = __builtin_amdgcn_mfma_f32_16x16x32_bf16(av, bv, ac, 0, 0, 0);
      }
      #pragma unroll
      for (int r = 0; r < 4; ++r) {
        const int rr = mt * 16 + lh * 4 + r;
        const int lel = (rr * 43) >> 7, il = rr - lel * 3;
        smF[(hb + lel) * SF + il * 32 + nt * 16 + ll] = ac[r];
      }
    }
    __syncthreads();
  }

  f32x4 acc[4];
  ZERO_ACC();
  float sumsq = 0.f;

  // ---- GEMM1: 12 K-stages; W(T) via reg-prefetch, X inline-staged ----
  #pragma unroll 1
  for (int T = 0; T < 12; ++T) {
    __syncthreads();                 // prior MFMA done reading Xl/Wl
    WPRE_STORE();                    // W(T) regs -> Wl
    {
      const float* fr = smF + j * SF;
      float xv[16];
      if (T < 8) {
        TRI16(T * 64 + w * 16);
      } else if (T == 8) {
        if (w == 0) {
          TRI16(512);
        } else if (w == 1) {
          const float4 v4 = *(const float4*)(edge_s + es_s[j] * 68 + 64);
          xv[0] = v4.x; xv[1] = v4.y; xv[2] = v4.z; xv[3] = v4.w;
          #pragma unroll
          for (int m = 4; m < 16; ++m) xv[m] = 0.f;
        } else {
          #pragma unroll
          for (int m = 0; m < 16; ++m) xv[m] = 0.f;
        }
      } else if (T == 9)  { XV_LOAD16(s + e0s[j] * 64 + w * 16); }
      else if (T == 10)   { XV_LOAD16(s + e1s[j] * 64 + w * 16); }
      else                { XV_LOAD16(edge_s + es_s[j] * 68 + w * 16); }
      PACK_STORE16(&Xl[j * STX + w * 16]);
    }
    __syncthreads();
    WPRE_LOAD(wbf + (T + 1) * 4096); // T=11 -> tile 12 (W2); hides under MFMA
    MFMA_K64();
  }

  // ---- h1 epilogue + Fn reduce; W2 arrives via last prefetch ----
  __syncthreads();
  red[w * 64 + j] = sumsq;
  #pragma unroll
  for (int nc = 0; nc < 4; ++nc) {
    const float bv = b1[nc * 16 + ll];
    #pragma unroll
    for (int r = 0; r < 4; ++r)
      Xl[(w * 16 + lh * 4 + r) * STX + nc * 16 + ll] = f2bf(fmaxf(acc[nc][r] + bv, 0.f));
  }
  WPRE_STORE();                      // W2 -> Wl (wpre dead afterwards)
  ZERO_ACC();
  __syncthreads();
  if (t < 64) {
    const float ss = red[t] + red[64 + t] + red[128 + t] + red[192 + t];
    iFn[t] = 1.f / (sqrtf(ss) + 1.f);
  }

  // ---- GEMM2 (h1 strip is wave-local) ----
  MFMA_K64();
  #pragma unroll
  for (int nc = 0; nc < 4; ++nc) {
    const float bv = b2[nc * 16 + ll];
    #pragma unroll
    for (int r = 0; r < 4; ++r)
      Xl[(w * 16 + lh * 4 + r) * STX + nc * 16 + ll] = f2bf(fmaxf(acc[nc][r] + bv, 0.f));
  }

  // ---- GEMM3 (17 n-tiles) + fused consume; direct stage (spill-free) ----
  float fcp[48];
  #pragma unroll
  for (int q = 0; q < 48; ++q) fcp[q] = 0.f;
  float csv[16];

  #pragma unroll 1
  for (int nt = 0; nt < 17; ++nt) {
    __syncthreads();                 // all waves done reading Wl
    STAGE_W(wbf + (13 + nt) * 4096);
    __syncthreads();
    ZERO_ACC();
    MFMA_K64();
    #pragma unroll
    for (int nc = 0; nc < 4; ++nc)
      #pragma unroll
      for (int r = 0; r < 4; ++r)
        C2h[(w * 16 + lh * 4 + r) * 65 + nc * 16 + ll] = f2bf(acc[nc][r]);
    // wave-private rows: no barrier needed before consume
    const float bv = b3[nt * 64 + j];
    if (nt < 16) {
      const int a_ = nt * 2 + (j >> 5);
      #pragma unroll
      for (int m = 0; m < 16; ++m) {
        const float cv = (bf2f(C2h[(eb + m) * 65 + j]) + bv) * iFn[eb + m];
        const float* fr = smF + (eb + m) * SF;
        fcp[m * 3 + 0] = fmaf(fr[a_],      cv, fcp[m * 3 + 0]);
        fcp[m * 3 + 1] = fmaf(fr[32 + a_], cv, fcp[m * 3 + 1]);
        fcp[m * 3 + 2] = fmaf(fr[64 + a_], cv, fcp[m * 3 + 2]);
      }
    } else {
      #pragma unroll
      for (int m = 0; m < 16; ++m)
        csv[m] = (bf2f(C2h[(eb + m) * 65 + j]) + bv) * iFn[eb + m];
    }
  }

  // ---- flush (verified R5): complete-run stores, partials via LDS merge ----
  __syncthreads();
  if (t < 8) snode[t] = -1;
  __syncthreads();

  {
    float r0 = 0.f, r1 = 0.f, r2 = 0.f, rs = 0.f;
    int runlen = 0;
    const int gwb = bid * 64 + eb;
    #pragma unroll
    for (int m = 0; m < 16; ++m) {
      float v0 = fcp[m * 3 + 0]; v0 += __shfl_xor(v0, 32);
      float v1 = fcp[m * 3 + 1]; v1 += __shfl_xor(v1, 32);
      float v2 = fcp[m * 3 + 2]; v2 += __shfl_xor(v2, 32);
      r0 += v0; r1 += v1; r2 += v2; rs += csv[m];
      ++runlen;
      const int n = e0s[eb + m];
      if (m == 15 || e0s[eb + m + 1] != n) {
        const int st = __shfl(str, m);
        const int dg = __shfl(dgr, m);
        const int g1v = gwb + m, g0v = g1v - runlen + 1;
        if (g0v == st && runlen == dg) {
          if (j < 32) {
            fc_sum[n * 96 + j]      = r0;
            fc_sum[n * 96 + 32 + j] = r1;
            fc_sum[n * 96 + 64 + j] = r2;
          }
          sc_sum[n * 64 + j] = rs;
        } else {
          const int slot = (g0v == gwb) ? 2 * w : 2 * w + 1;
          if (j < 32) {
            fcpart[slot * 96 + j]      = r0;
            fcpart[slot * 96 + 32 + j] = r1;
            fcpart[slot * 96 + 64 + j] = r2;
          }
          scpart[slot * 64 + j] = rs;
          if (j == 0) { snode[slot] = n; sst[slot] = st; sdg[slot] = dg; }
        }
        r0 = r1 = r2 = rs = 0.f; runlen = 0;
      }
    }
  }
  __syncthreads();

  if (t < 160) {
    const int ch = t;
    int prevn = -1;
    #pragma unroll 1
    for (int ss = 0; ss < 8; ++ss) {
      const int n = snode[ss];
      if (n < 0) { continue; }
      if (n != prevn) {
        float v = (ch < 96) ? fcpart[ss * 96 + ch] : scpart[ss * 64 + (ch - 96)];
        #pragma unroll 1
        for (int k2 = ss + 1; k2 < 8; ++k2) {
          if (snode[k2] == n)
            v += (ch < 96) ? fcpart[k2 * 96 + ch] : scpart[k2 * 64 + (ch - 96)];
          else if (snode[k2] >= 0) break;
        }
        const bool cib = (sst[ss] >= bid * 64) && (sst[ss] + sdg[ss] <= bid * 64 + 64);
        float* dst = (ch < 96) ? (fc_sum + n * 96 + ch) : (sc_sum + n * 64 + (ch - 96));
        if (cib) *dst = v; else atomicAdd(dst, v);
      }
      prevn = n;
    }
  }
}

// sums -> means
__global__ __launch_bounds__(256)
void sgnn_norm(float* __restrict__ fcm, float* __restrict__ scm,
               const int* __restrict__ deg) {
  const int idx = blockIdx.x * 256 + threadIdx.x;
  if (idx >= NN * 160) return;
  const int n = idx / 160, c = idx % 160;
  const float ic = 1.f / fmaxf((float)deg[n], 1.f);
  if (c < 96) fcm[n * 96 + c] *= ic;
  else        scm[n * 64 + (c - 96)] *= ic;
}

__global__ __launch_bounds__(256, 2)
void sgnn_node(const float* __restrict__ f, const float* __restrict__ s,
               const float* __restrict__ b1, const float* __restrict__ b2,
               const float* __restrict__ b3,
               const ushort* __restrict__ wbf, const ushort* __restrict__ tab_g,
               const float* __restrict__ fcm, const float* __restrict__ scm,
               float* __restrict__ of, float* __restrict__ os) {
  __shared__ __align__(16) char sbuf[LDS_BYTES];
  float*  smF  = (float*)sbuf;
  ushort* Xl   = (ushort*)(sbuf + 24832);
  ushort* Wl   = (ushort*)(sbuf + 34048);
  ushort* Aemb = (ushort*)(sbuf + 24832);  // embed A [96][SAN]
  float*  red  = (float*)(sbuf + 43264);
  ushort* C2h  = (ushort*)(sbuf + 43264);
  ushort* tabL = (ushort*)(sbuf + 51584);
  float*  iFn  = (float*)(sbuf + 51584);

  const int t = threadIdx.x, j = t & 63, w = t >> 6, eb = w * 16;
  const int lh = j >> 4, ll = j & 15;
  const int nbase = blockIdx.x * 64;
  const ushort* wembTn = wbf + 60 * 4096;  // Wemb2^T [32 col][64 k]
  short8v wpre0, wpre1;

  for (int idx = t; idx < NTRI; idx += 256) tabL[idx] = tab_g[idx];
  WPRE_LOAD(wbf + 30 * 4096);
  __syncthreads();

  // ---- MFMA embed: smF = concat(f, f_c_mean) @ Wemb2, 2 halves ----
  #pragma unroll 1
  for (int h = 0; h < 2; ++h) {
    const int hb = h * 32;
    #pragma unroll 1
    for (int cc = t; cc < 384; cc += 256) {    // 96 rows x 4 k-segs
      const int row = cc >> 2, seg = cc & 3;
      const int lel = (row * 43) >> 7, il = row - lel * 3;
      const int nc = min(nbase + hb + lel, NN - 1);
      const int k0 = seg * 16;
      float xv[16];
      const float* p = (seg < 2) ? (f + nc * 96 + il * 32 + seg * 16)
                                 : (fcm + nc * 96 + il * 32 + (seg - 2) * 16);
      XV_LOAD16(p);
      PACK_STORE16(&Aemb[row * SAN + k0]);
    }
    __syncthreads();
    #pragma unroll 1
    for (int job = w * 3; job < w * 3 + 3; ++job) {
      const int mt = job >> 1, nt = job & 1;
      f32x4 ac = (f32x4){0.f, 0.f, 0.f, 0.f};
      #pragma unroll
      for (int kb = 0; kb < 2; ++kb) {
        const bf16x8 av = *(const bf16x8*)&Aemb[(mt * 16 + ll) * SAN + kb * 32 + lh * 8];
        const bf16x8 bv = *(const bf16x8*)&wembTn[(nt * 16 + ll) * 64 + kb * 32 + lh * 8];
        ac = __builtin_amdgcn_mfma_f32_16x16x32_bf16(av, bv, ac, 0, 0, 0);
      }
      #pragma unroll
      for (int r = 0; r < 4; ++r) {
        const int rr = mt * 16 + lh * 4 + r;
        const int lel = (rr * 43) >> 7, il = rr - lel * 3;
        smF[(hb + lel) * SF + il * 32 + nt * 16 + ll] = ac[r];
      }
    }
    __syncthreads();
  }

  f32x4 acc[4];
  ZERO_ACC();
  float sumsq = 0.f;

  // ---- GEMM1: 11 K-stages ----
  #pragma unroll 1
  for (int T = 0; T < 11; ++T) {
    __syncthreads();
    WPRE_STORE();
    {
      const float* fr = smF + j * SF;
      float xv[16];
      if (T < 8) {
        TRI16(T * 64 + w * 16);
      } else if (T == 8) {
        if (w == 0) {
          TRI16(512);
        } else {
          #pragma unroll
          for (int m = 0; m < 16; ++m) xv[m] = 0.f;
        }
      } else if (T == 9) {
        XV_LOAD16(s + min(nbase + j, NN - 1) * 64 + w * 16);
      } else {
        XV_LOAD16(scm + min(nbase + j, NN - 1) * 64 + w * 16);
      }
      PACK_STORE16(&Xl[j * STX + w * 16]);
    }
    __syncthreads();
    WPRE_LOAD(wbf + (31 + T) * 4096);  // T=10 -> tile 41 (W2)
    MFMA_K64();
  }

  __syncthreads();
  red[w * 64 + j] = sumsq;
  #pragma unroll
  for (int nc = 0; nc < 4; ++nc) {
    const float bv = b1[nc * 16 + ll];
    #pragma unroll
    for (int r = 0; r < 4; ++r)
      Xl[(w * 16 + lh * 4 + r) * STX + nc * 16 + ll] = f2bf(fmaxf(acc[nc][r] + bv, 0.f));
  }
  WPRE_STORE();                      // W2
  ZERO_ACC();
  __syncthreads();
  if (t < 64) {
    const float ss = red[t] + red[64 + t] + red[128 + t] + red[192 + t];
    iFn[t] = 1.f / (sqrtf(ss) + 1.f);
  }

  MFMA_K64();                        // GEMM2
  #pragma unroll
  for (int nc = 0; nc < 4; ++nc) {
    const float bv = b2[nc * 16 + ll];
    #pragma unroll
    for (int r = 0; r < 4; ++r)
      Xl[(w * 16 + lh * 4 + r) * STX + nc * 16 + ll] = f2bf(fmaxf(acc[nc][r] + bv, 0.f));
  }

  float fcp[48];
  #pragma unroll
  for (int q = 0; q < 48; ++q) fcp[q] = 0.f;

  #pragma unroll 1
  for (int nt = 0; nt < 17; ++nt) {
    __syncthreads();
    STAGE_W(wbf + (42 + nt) * 4096);
    __syncthreads();
    ZERO_ACC();
    MFMA_K64();
    #pragma unroll
    for (int nc = 0; nc < 4; ++nc)
      #pragma unroll
      for (int r = 0; r < 4; ++r)
        C2h[(w * 16 + lh * 4 + r) * 65 + nc * 16 + ll] = f2bf(acc[nc][r]);
    const float bv = b3[nt * 64 + j];
    if (nt < 16) {
      const int a_ = nt * 2 + (j >> 5);
      #pragma unroll
      for (int m = 0; m < 16; ++m) {
        const float cv = (bf2f(C2h[(eb + m) * 65 + j]) + bv) * iFn[eb + m];
        const float* fr = smF + (eb + m) * SF;
        fcp[m * 3 + 0] = fmaf(fr[a_],      cv, fcp[m * 3 + 0]);
        fcp[m * 3 + 1] = fmaf(fr[32 + a_], cv, fcp[m * 3 + 1]);
        fcp[m * 3 + 2] = fmaf(fr[64 + a_], cv, fcp[m * 3 + 2]);
      }
    } else {
      #pragma unroll
      for (int m = 0; m < 16; ++m) {
        const int n_m = nbase + eb + m;
        const float cv = (bf2f(C2h[(eb + m) * 65 + j]) + bv) * iFn[eb + m];
        if (n_m < NN) os[n_m * 64 + j] = cv + s[n_m * 64 + j];
      }
    }
  }

  {
    const int b_ = j & 31;
    #pragma unroll
    for (int m = 0; m < 16; ++m) {
      const int n_m = nbase + eb + m;
      #pragma unroll
      for (int i = 0; i < 3; ++i) {
        float v = fcp[m * 3 + i];
        v += __shfl_xor(v, 32);
        if (j < 32 && n_m < NN)
          of[n_m * 96 + i * 32 + b_] = v + f[n_m * 96 + i * 32 + b_];
      }
    }
  }
}

extern "C" void kernel_launch(void* const* d_in, const int* in_sizes, int n_in,
                              void* d_out, int out_size, void* d_ws, size_t ws_size,
                              hipStream_t stream) {
  const float* f      = (const float*)d_in[0];
  const float* s      = (const float*)d_in[1];
  const float* edge_f = (const float*)d_in[2];
  const float* edge_s = (const float*)d_in[3];
  const float* Wemb1  = (const float*)d_in[4];
  const float* nW1 = (const float*)d_in[5];
  const float* nb1 = (const float*)d_in[6];
  const float* nW2 = (const float*)d_in[7];
  const float* nb2 = (const float*)d_in[8];
  const float* nW3 = (const float*)d_in[9];
  const float* nb3 = (const float*)d_in[10];
  const float* Wemb2 = (const float*)d_in[11];
  const float* sW1 = (const float*)d_in[12];
  const float* sb1 = (const float*)d_in[13];
  const float* sW2 = (const float*)d_in[14];
  const float* sb2 = (const float*)d_in[15];
  const float* sW3 = (const float*)d_in[16];
  const float* sb3 = (const float*)d_in[17];
  const int* eidx  = (const int*)d_in[18];

  float* of = (float*)d_out;               // [NN*96] ; aliases fc mean
  float* os = of + (size_t)NN * 96;        // [NN*64] ; aliases sc mean

  // ws: deg[NN] | cursor[NN] | start[NN] | sorted[NE] | wbf[61*4096] | tab[528]
  int* deg    = (int*)d_ws;
  int* cursor = deg + NN;
  int* start  = cursor + NN;
  int* sorted = start + NN;
  ushort* wbf = (ushort*)(sorted + NE);
  ushort* tab = wbf + 61 * 4096;

  hipMemsetAsync(deg, 0, (size_t)NN * 4, stream);
  hipMemsetAsync(d_out, 0, (size_t)NN * 160 * 4, stream);

  hipLaunchKernelGGL(sgnn_wconv, dim3((61 * 4096 + NTRI + 255) / 256), dim3(256),
                     0, stream, nW1, nW2, nW3, sW1, sW2, sW3, Wemb1, Wemb2,
                     wbf, tab);
  hipLaunchKernelGGL(sgnn_hist, dim3((NE + 255) / 256), dim3(256), 0, stream,
                     eidx, deg);
  hipLaunchKernelGGL(sgnn_scan, dim3(1), dim3(1024), 0, stream, deg, cursor, start);
  hipLaunchKernelGGL(sgnn_scatter, dim3((NE + 255) / 256), dim3(256), 0, stream,
                     eidx, cursor, sorted);
  hipLaunchKernelGGL(sgnn_edge, dim3(NE / 64), dim3(256), 0, stream,
                     f, s, edge_f, edge_s, nb1, nb2, nb3,
                     wbf, tab, eidx, sorted, start, deg,
                     of /*fc_sum*/, os /*sc_sum*/);
  hipLaunchKernelGGL(sgnn_norm, dim3((NN * 160 + 255) / 256), dim3(256), 0, stream,
                     of, os, deg);
  hipLaunchKernelGGL(sgnn_node, dim3((NN + 63) / 64), dim3(256), 0, stream,
                     f, s, sb1, sb2, sb3,
                     wbf, tab, of /*fcm*/, os /*scm*/, of, os);
}

// Round 11
// 210.833 us; speedup vs baseline: 1.6487x; 1.1312x over previous
//
#include <hip/hip_runtime.h>
#include <math.h>

#define NN 10000
#define NE 80000
#define SF 98    // smF row stride (f32): even (b64-aligned pairs), 98%32=2 -> 2-way max
#define SFF 97   // F flush-buffer stride (f32)
#define STX 72   // bf16 tile row stride (144B rows, 16B-aligned)
#define NTRI 528 // 32*33/2 unique Gram entries
#define SAE 104  // edge embed A stride (bf16)
#define SAN 72   // node embed A stride (bf16)

typedef __attribute__((ext_vector_type(8))) __bf16 bf16x8;
typedef __attribute__((ext_vector_type(8))) short short8v;
typedef __attribute__((ext_vector_type(4))) float f32x4;
typedef __attribute__((ext_vector_type(4))) unsigned uint4v;

__device__ __forceinline__ ushort f2bf(float x) {
  union { float f; unsigned u; } v; v.f = x;
  unsigned r = v.u + 0x7FFFu + ((v.u >> 16) & 1u);
  return (ushort)(r >> 16);
}
__device__ __forceinline__ void tri_ab(int k, int& a, int& b) {
  int aa = 0, rem = k;
  while (rem >= 32 - aa) { rem -= 32 - aa; ++aa; }
  a = aa; b = aa + rem;
}

// ---- sort edges by e0 (verified R2/R3) ----
__global__ __launch_bounds__(256)
void sgnn_hist(const int* __restrict__ eidx, int* __restrict__ deg) {
  const int e = blockIdx.x * 256 + threadIdx.x;
  if (e < NE) atomicAdd(deg + eidx[e], 1);
}

__global__ __launch_bounds__(1024)
void sgnn_scan(const int* __restrict__ deg, int* __restrict__ cursor,
               int* __restrict__ start) {
  __shared__ int sm[1024];
  __shared__ int carry;
  const int t = threadIdx.x;
  if (t == 0) carry = 0;
  __syncthreads();
  for (int base = 0; base < NN; base += 1024) {
    const int i = base + t;
    const int v = (i < NN) ? deg[i] : 0;
    sm[t] = v;
    __syncthreads();
    #pragma unroll
    for (int d = 1; d < 1024; d <<= 1) {
      const int add = (t >= d) ? sm[t - d] : 0;
      __syncthreads();
      sm[t] += add;
      __syncthreads();
    }
    const int excl = carry + sm[t] - v;
    if (i < NN) { cursor[i] = excl; start[i] = excl; }
    __syncthreads();
    if (t == 1023) carry += sm[1023];
    __syncthreads();
  }
}

__global__ __launch_bounds__(256)
void sgnn_scatter(const int* __restrict__ eidx, int* __restrict__ cursor,
                  int* __restrict__ sorted) {
  const int e = blockIdx.x * 256 + threadIdx.x;
  if (e < NE) {
    const int p = atomicAdd(cursor + eidx[e], 1);
    sorted[p] = e;
  }
}

// ---- weight convert: blocked bf16 tiles; +59: Wemb1^T [32][96], +60: Wemb2^T [32][64]
__global__ __launch_bounds__(256)
void sgnn_wconv(const float* __restrict__ nW1, const float* __restrict__ nW2,
                const float* __restrict__ nW3, const float* __restrict__ sW1,
                const float* __restrict__ sW2, const float* __restrict__ sW3,
                const float* __restrict__ Wemb1, const float* __restrict__ Wemb2,
                ushort* __restrict__ wout, ushort* __restrict__ tab) {
  const int gid = blockIdx.x * 256 + threadIdx.x;
  if (gid >= 61 * 4096) {
    const int k = gid - 61 * 4096;
    if (k < NTRI) {
      int a, b; tri_ab(k, a, b);
      tab[k] = (ushort)(a | (b << 8) | ((a != b) ? 0x8000 : 0));
    }
    return;
  }
  const int tile = gid >> 12, idx = gid & 4095;
  const int c = idx >> 6, k = idx & 63;
  float v = 0.f;
  if (tile < 12) {
    const int T = tile;
    if (T < 8 || (T == 8 && k < 16)) {
      const int ktri = T * 64 + k;
      if (ktri < NTRI) {
        int a, b; tri_ab(ktri, a, b);
        v = nW1[(a * 32 + b) * 64 + c];
        if (a != b) v += nW1[(b * 32 + a) * 64 + c];
      }
    } else if (T == 8) { if (k < 20) v = nW1[(1216 + (k - 16)) * 64 + c]; }
    else if (T == 9)   v = nW1[(1024 + k) * 64 + c];
    else if (T == 10)  v = nW1[(1088 + k) * 64 + c];
    else               v = nW1[(1152 + k) * 64 + c];
  } else if (tile == 12) v = nW2[k * 64 + c];
  else if (tile < 30)    v = nW3[k * 1088 + (tile - 13) * 64 + c];
  else if (tile < 41) {
    const int T = tile - 30;
    if (T < 8 || (T == 8 && k < 16)) {
      const int ktri = T * 64 + k;
      if (ktri < NTRI) {
        int a, b; tri_ab(ktri, a, b);
        v = sW1[(a * 32 + b) * 64 + c];
        if (a != b) v += sW1[(b * 32 + a) * 64 + c];
      }
    } else if (T == 9) v = sW1[(1024 + k) * 64 + c];
    else if (T == 10)  v = sW1[(1088 + k) * 64 + c];
  } else if (tile == 41) v = sW2[k * 64 + c];
  else if (tile < 59)    v = sW3[k * 1088 + (tile - 42) * 64 + c];
  else if (tile == 59) {
    const int col = idx / 96, kk = idx % 96;
    v = (col < 32 && kk < 65) ? Wemb1[kk * 32 + col] : 0.f;
  } else {
    const int col = idx >> 6;
    v = (col < 32) ? Wemb2[k * 32 + col] : 0.f;
  }
  wout[gid] = f2bf(v);
}

#define STAGE_W(srcbase) do { const ushort* _s = (srcbase);                      \
  _Pragma("unroll") for (int rr = 0; rr < 2; ++rr) {                             \
    const int idx_ = t + 256 * rr; const int c_ = idx_ >> 3, ko_ = idx_ & 7;     \
    *(short8v*)&Wl[c_ * STX + ko_ * 8] = *(const short8v*)&_s[c_ * 64 + ko_ * 8];\
  } } while (0)

#define WPRE_LOAD(srcbase) do { const ushort* _s = (srcbase);                    \
  wpre0 = *(const short8v*)&_s[(t >> 3) * 64 + (t & 7) * 8];                     \
  wpre1 = *(const short8v*)&_s[(32 + (t >> 3)) * 64 + (t & 7) * 8]; } while (0)

#define WPRE_STORE() do {                                                        \
  *(short8v*)&Wl[(t >> 3) * STX + (t & 7) * 8] = wpre0;                          \
  *(short8v*)&Wl[(32 + (t >> 3)) * STX + (t & 7) * 8] = wpre1; } while (0)

#define MFMA_K64() do {                                                          \
  _Pragma("unroll") for (int kb = 0; kb < 2; ++kb) {                             \
    const bf16x8 af_ = *(const bf16x8*)&Xl[(w * 16 + ll) * STX + kb * 32 + lh * 8]; \
    acc[0] = __builtin_amdgcn_mfma_f32_16x16x32_bf16(af_,                        \
        *(const bf16x8*)&Wl[(     ll) * STX + kb * 32 + lh * 8], acc[0], 0, 0, 0); \
    acc[1] = __builtin_amdgcn_mfma_f32_16x16x32_bf16(af_,                        \
        *(const bf16x8*)&Wl[(16 + ll) * STX + kb * 32 + lh * 8], acc[1], 0, 0, 0); \
    acc[2] = __builtin_amdgcn_mfma_f32_16x16x32_bf16(af_,                        \
        *(const bf16x8*)&Wl[(32 + ll) * STX + kb * 32 + lh * 8], acc[2], 0, 0, 0); \
    acc[3] = __builtin_amdgcn_mfma_f32_16x16x32_bf16(af_,                        \
        *(const bf16x8*)&Wl[(48 + ll) * STX + kb * 32 + lh * 8], acc[3], 0, 0, 0); \
  } } while (0)

#define ZERO_ACC() do { _Pragma("unroll") for (int q = 0; q < 4; ++q)            \
    acc[q] = (f32x4){0.f, 0.f, 0.f, 0.f}; } while (0)

#define PACK_STORE16(dstp) do {                                                  \
  unsigned pk[8];                                                                \
  _Pragma("unroll") for (int q = 0; q < 8; ++q)                                  \
    pk[q] = (unsigned)f2bf(xv[2 * q]) | ((unsigned)f2bf(xv[2 * q + 1]) << 16);   \
  *(uint4v*)(dstp)       = (uint4v){pk[0], pk[1], pk[2], pk[3]};                 \
  *(uint4v*)((dstp) + 8) = (uint4v){pk[4], pk[5], pk[6], pk[7]};                 \
} while (0)

#define TRI16(kt) do {                                                           \
  int prev_a = -1; float fa0 = 0.f, fa1 = 0.f, fa2 = 0.f;                        \
  _Pragma("unroll") for (int m = 0; m < 16; ++m) {                               \
    const int tb = tabL[(kt) + m];                                               \
    const int a_ = tb & 31, b_ = (tb >> 8) & 31;                                 \
    if (a_ != prev_a) { fa0 = fr[a_]; fa1 = fr[32 + a_]; fa2 = fr[64 + a_];      \
                        prev_a = a_; }                                           \
    const float v = fmaf(fa0, fr[b_],                                            \
        fmaf(fa1, fr[32 + b_], fa2 * fr[64 + b_]));                              \
    const float wsel = (tb & 0x8000) ? 2.f : 1.f;                                \
    sumsq = fmaf(v * wsel, v, sumsq);                                            \
    xv[m] = v;                                                                   \
  } } while (0)

#define XV_LOAD16(p) do { const float* _p = (p);                                 \
  _Pragma("unroll") for (int q = 0; q < 4; ++q) {                                \
    const float4 v4 = *(const float4*)(_p + 4 * q);                              \
    xv[4 * q + 0] = v4.x; xv[4 * q + 1] = v4.y;                                  \
    xv[4 * q + 2] = v4.z; xv[4 * q + 3] = v4.w; } } while (0)

// holder-side consume for one n-tile (nt<16): fch[(r*3+i)*2+p] over a,b
#define CONSUME_NT() do {                                                        \
  _Pragma("unroll") for (int r = 0; r < 4; ++r) {                                \
    const int row_ = w * 16 + lh * 4 + r;                                        \
    float2 fr2_0 = *(const float2*)&smF[row_ * SF +      nt * 2];                \
    float2 fr2_1 = *(const float2*)&smF[row_ * SF + 32 + nt * 2];                \
    float2 fr2_2 = *(const float2*)&smF[row_ * SF + 64 + nt * 2];                \
    _Pragma("unroll") for (int nc = 0; nc < 4; ++nc) {                           \
      const float cv = (acc[nc][r] + b3v[nc]) * ifnr[r];                         \
      const int p = nc & 1;                                                      \
      const float f0 = (nc < 2) ? fr2_0.x : fr2_0.y;                             \
      const float f1 = (nc < 2) ? fr2_1.x : fr2_1.y;                             \
      const float f2 = (nc < 2) ? fr2_2.x : fr2_2.y;                             \
      fch[(r * 3 + 0) * 2 + p] = fmaf(f0, cv, fch[(r * 3 + 0) * 2 + p]);         \
      fch[(r * 3 + 1) * 2 + p] = fmaf(f1, cv, fch[(r * 3 + 1) * 2 + p]);         \
      fch[(r * 3 + 2) * 2 + p] = fmaf(f2, cv, fch[(r * 3 + 2) * 2 + p]);         \
    }                                                                            \
  } } while (0)

// stage fch/cs to F/S flush buffers (holder layout -> channel layout)
#define STAGE_FS() do {                                                          \
  _Pragma("unroll") for (int r = 0; r < 4; ++r) {                                \
    const int row_ = w * 16 + lh * 4 + r;                                        \
    _Pragma("unroll") for (int i = 0; i < 3; ++i) {                              \
      F[row_ * SFF + i * 32 + ll]      = fch[(r * 3 + i) * 2 + 0];               \
      F[row_ * SFF + i * 32 + ll + 16] = fch[(r * 3 + i) * 2 + 1];               \
    }                                                                            \
    _Pragma("unroll") for (int nc = 0; nc < 4; ++nc)                             \
      S[row_ * 65 + nc * 16 + ll] = cs[nc * 4 + r];                              \
  } } while (0)

// LDS carve (46624 B -> 3 blocks/CU)
//  0      smF [64][98] f32 25088 / F [64][97] f32 24832 (flush)
//  25088  Xl 9216 | Wl 9216 (43520) / Aemb(embed, reach 45056) / S [64][65] 16640
//  43520  red f32[256] / icntL(node) / flush meta (5x8 int)
//  45056  tabL[528] us (1056) / iFn f32[64] (post-GEMM1)
//  46112  es_s[64] int | 46368 e0s[64] us | 46496 e1s[64] us
#define LDS_BYTES 46624

__global__ __launch_bounds__(256, 2)
void sgnn_edge(const float* __restrict__ f, const float* __restrict__ s,
               const float* __restrict__ edge_f, const float* __restrict__ edge_s,
               const float* __restrict__ b1, const float* __restrict__ b2,
               const float* __restrict__ b3,
               const ushort* __restrict__ wbf, const ushort* __restrict__ tab_g,
               const int* __restrict__ eidx, const int* __restrict__ sorted,
               const int* __restrict__ start_g, const int* __restrict__ deg_g,
               float* __restrict__ fc_sum, float* __restrict__ sc_sum) {
  __shared__ __align__(16) char sbuf[LDS_BYTES];
  float*  smF  = (float*)sbuf;
  float*  F    = (float*)sbuf;             // flush overlay
  ushort* Xl   = (ushort*)(sbuf + 25088);
  ushort* Wl   = (ushort*)(sbuf + 34304);
  ushort* Aemb = (ushort*)(sbuf + 25088);  // embed A [96][SAE]
  float*  S    = (float*)(sbuf + 25088);   // flush overlay [64][65]
  float*  red  = (float*)(sbuf + 43520);
  int*    snode = (int*)(sbuf + 43520);    // flush meta (red dead)
  int*    srow0 = snode + 8;
  int*    srow1 = snode + 16;
  int*    sst   = snode + 24;
  int*    sdg   = snode + 32;
  ushort* tabL = (ushort*)(sbuf + 45056);
  float*  iFn  = (float*)(sbuf + 45056);   // overlays tab after GEMM1
  int*    es_s = (int*)(sbuf + 46112);
  ushort* e0s  = (ushort*)(sbuf + 46368);
  ushort* e1s  = (ushort*)(sbuf + 46496);

  const int t = threadIdx.x, j = t & 63, w = t >> 6, eb = w * 16;
  const int lh = j >> 4, ll = j & 15;
  const int bid = blockIdx.x;
  const ushort* wembT = wbf + 59 * 4096;
  short8v wpre0, wpre1;

  if (t < 64) {
    const int e = sorted[bid * 64 + t];
    es_s[t] = e;
    e0s[t] = (ushort)eidx[e];
    e1s[t] = (ushort)eidx[NE + e];
  }
  for (int idx = t; idx < NTRI; idx += 256) tabL[idx] = tab_g[idx];
  __syncthreads();

  int str = 0, dgr = 0;
  if (j < 16) {
    const int n_ = e0s[eb + j];
    str = start_g[n_];
    dgr = deg_g[n_];
  }
  WPRE_LOAD(wbf + 0);

  // ---- MFMA embed (verified R9): smF = concat(f[e0],f[e1],edge_f) @ Wemb1 ----
  #pragma unroll 1
  for (int h = 0; h < 2; ++h) {
    const int hb = h * 32;
    #pragma unroll 1
    for (int cc = t; cc < 576; cc += 256) {
      const int row = cc / 6, seg = cc - row * 6;
      const int lel = (row * 43) >> 7, il = row - lel * 3;
      const int k0 = seg * 16;
      float xv[16];
      if (seg < 4) {
        const int nd = (seg < 2) ? (int)e0s[hb + lel] : (int)e1s[hb + lel];
        XV_LOAD16(f + nd * 96 + il * 32 + (seg & 1) * 16);
      } else if (seg == 4) {
        xv[0] = edge_f[es_s[hb + lel] * 3 + il];
        #pragma unroll
        for (int m = 1; m < 16; ++m) xv[m] = 0.f;
      } else {
        #pragma unroll
        for (int m = 0; m < 16; ++m) xv[m] = 0.f;
      }
      PACK_STORE16(&Aemb[row * SAE + k0]);
    }
    __syncthreads();
    #pragma unroll 1
    for (int job = w * 3; job < w * 3 + 3; ++job) {
      const int mt = job >> 1, nt = job & 1;
      f32x4 ac = (f32x4){0.f, 0.f, 0.f, 0.f};
      #pragma unroll
      for (int kb = 0; kb < 3; ++kb) {
        const bf16x8 av = *(const bf16x8*)&Aemb[(mt * 16 + ll) * SAE + kb * 32 + lh * 8];
        const bf16x8 bv = *(const bf16x8*)&wembT[(nt * 16 + ll) * 96 + kb * 32 + lh * 8];
        ac = __builtin_amdgcn_mfma_f32_16x16x32_bf16(av, bv, ac, 0, 0, 0);
      }
      #pragma unroll
      for (int r = 0; r < 4; ++r) {
        const int rr = mt * 16 + lh * 4 + r;
        const int lel = (rr * 43) >> 7, il = rr - lel * 3;
        smF[(hb + lel) * SF + il * 32 + nt * 16 + ll] = ac[r];
      }
    }
    __syncthreads();
  }

  f32x4 acc[4];
  ZERO_ACC();
  float sumsq = 0.f;

  // ---- GEMM1: 12 K-stages (verified R8/R9) ----
  #pragma unroll 1
  for (int T = 0; T < 12; ++T) {
    __syncthreads();
    WPRE_STORE();
    {
      const float* fr = smF + j * SF;
      float xv[16];
      if (T < 8) {
        TRI16(T * 64 + w * 16);
      } else if (T == 8) {
        if (w == 0) {
          TRI16(512);
        } else if (w == 1) {
          const float4 v4 = *(const float4*)(edge_s + es_s[j] * 68 + 64);
          xv[0] = v4.x; xv[1] = v4.y; xv[2] = v4.z; xv[3] = v4.w;
          #pragma unroll
          for (int m = 4; m < 16; ++m) xv[m] = 0.f;
        } else {
          #pragma unroll
          for (int m = 0; m < 16; ++m) xv[m] = 0.f;
        }
      } else if (T == 9)  { XV_LOAD16(s + e0s[j] * 64 + w * 16); }
      else if (T == 10)   { XV_LOAD16(s + e1s[j] * 64 + w * 16); }
      else                { XV_LOAD16(edge_s + es_s[j] * 68 + w * 16); }
      PACK_STORE16(&Xl[j * STX + w * 16]);
    }
    __syncthreads();
    WPRE_LOAD(wbf + (T + 1) * 4096);
    MFMA_K64();
  }

  // ---- h1 epilogue + Fn reduce ----
  __syncthreads();
  red[w * 64 + j] = sumsq;
  #pragma unroll
  for (int nc = 0; nc < 4; ++nc) {
    const float bv = b1[nc * 16 + ll];
    #pragma unroll
    for (int r = 0; r < 4; ++r)
      Xl[(w * 16 + lh * 4 + r) * STX + nc * 16 + ll] = f2bf(fmaxf(acc[nc][r] + bv, 0.f));
  }
  WPRE_STORE();
  ZERO_ACC();
  __syncthreads();
  if (t < 64) {
    const float ss = red[t] + red[64 + t] + red[128 + t] + red[192 + t];
    iFn[t] = 1.f / (sqrtf(ss) + 1.f);
  }

  // ---- GEMM2 ----
  MFMA_K64();
  #pragma unroll
  for (int nc = 0; nc < 4; ++nc) {
    const float bv = b2[nc * 16 + ll];
    #pragma unroll
    for (int r = 0; r < 4; ++r)
      Xl[(w * 16 + lh * 4 + r) * STX + nc * 16 + ll] = f2bf(fmaxf(acc[nc][r] + bv, 0.f));
  }

  // ---- GEMM3: holder-side consume (no C2 roundtrip) ----
  float fch[24];
  #pragma unroll
  for (int q = 0; q < 24; ++q) fch[q] = 0.f;
  float cs[16];
  float ifnr[4];

  #pragma unroll 1
  for (int nt = 0; nt < 17; ++nt) {
    __syncthreads();
    STAGE_W(wbf + (13 + nt) * 4096);
    float b3v[4];
    #pragma unroll
    for (int nc = 0; nc < 4; ++nc) b3v[nc] = b3[nt * 64 + nc * 16 + ll];
    __syncthreads();
    if (nt == 0) {
      #pragma unroll
      for (int r = 0; r < 4; ++r) ifnr[r] = iFn[w * 16 + lh * 4 + r];
    }
    ZERO_ACC();
    MFMA_K64();
    if (nt < 16) {
      CONSUME_NT();
    } else {
      #pragma unroll
      for (int nc = 0; nc < 4; ++nc)
        #pragma unroll
        for (int r = 0; r < 4; ++r)
          cs[nc * 4 + r] = (acc[nc][r] + b3v[nc]) * ifnr[r];
    }
  }

  // ---- stage F/S, then run-flush (verified R5 logic, reading F/S) ----
  __syncthreads();
  STAGE_FS();
  if (t < 8) snode[t] = -1;
  __syncthreads();

  {
    float r0 = 0.f, r1 = 0.f, rs = 0.f;
    int runlen = 0;
    const int gwb = bid * 64 + eb;
    #pragma unroll 1
    for (int m = 0; m < 16; ++m) {
      const int row = eb + m;
      r0 += F[row * SFF + j];
      if (j < 32) r1 += F[row * SFF + 64 + j];
      rs += S[row * 65 + j];
      ++runlen;
      const int n = e0s[row];
      if (m == 15 || e0s[row + 1] != n) {
        const int st = __shfl(str, m);
        const int dg = __shfl(dgr, m);
        const int g1v = gwb + m, g0v = g1v - runlen + 1;
        if (g0v == st && runlen == dg) {
          fc_sum[n * 96 + j] = r0;
          if (j < 32) fc_sum[n * 96 + 64 + j] = r1;
          sc_sum[n * 64 + j] = rs;
        } else {
          const int slot = (g0v == gwb) ? 2 * w : 2 * w + 1;
          if (j == 0) {
            snode[slot] = n; srow0[slot] = row - runlen + 1; srow1[slot] = row;
            sst[slot] = st; sdg[slot] = dg;
          }
        }
        r0 = r1 = rs = 0.f; runlen = 0;
      }
    }
  }
  __syncthreads();

  if (t < 160) {
    const int ch = t;
    int prevn = -1;
    #pragma unroll 1
    for (int ss = 0; ss < 8; ++ss) {
      const int n = snode[ss];
      if (n < 0) continue;
      if (n != prevn) {
        float v = 0.f;
        #pragma unroll 1
        for (int k2 = ss; k2 < 8; ++k2) {
          if (snode[k2] == n) {
            #pragma unroll 1
            for (int row = srow0[k2]; row <= srow1[k2]; ++row)
              v += (ch < 96) ? F[row * SFF + ch] : S[row * 65 + (ch - 96)];
          } else if (k2 > ss && snode[k2] >= 0) break;
        }
        const bool cib = (sst[ss] >= bid * 64) && (sst[ss] + sdg[ss] <= bid * 64 + 64);
        float* dst = (ch < 96) ? (fc_sum + n * 96 + ch) : (sc_sum + n * 64 + (ch - 96));
        if (cib) *dst = v; else atomicAdd(dst, v);
      }
      prevn = n;
    }
  }
}

__global__ __launch_bounds__(256, 2)
void sgnn_node(const float* __restrict__ f, const float* __restrict__ s,
               const float* __restrict__ b1, const float* __restrict__ b2,
               const float* __restrict__ b3,
               const ushort* __restrict__ wbf, const ushort* __restrict__ tab_g,
               const float* __restrict__ fcm, const float* __restrict__ scm,
               const int* __restrict__ deg_g,
               float* __restrict__ of, float* __restrict__ os) {
  __shared__ __align__(16) char sbuf[LDS_BYTES];
  float*  smF  = (float*)sbuf;
  float*  F    = (float*)sbuf;
  ushort* Xl   = (ushort*)(sbuf + 25088);
  ushort* Wl   = (ushort*)(sbuf + 34304);
  ushort* Aemb = (ushort*)(sbuf + 25088);
  float*  S    = (float*)(sbuf + 25088);
  float*  red  = (float*)(sbuf + 43520);
  float*  icntL = (float*)(sbuf + 43520); // dead before red written
  ushort* tabL = (ushort*)(sbuf + 45056);
  float*  iFn  = (float*)(sbuf + 45056);

  const int t = threadIdx.x, j = t & 63, w = t >> 6, eb = w * 16;
  const int lh = j >> 4, ll = j & 15;
  const int nbase = blockIdx.x * 64;
  const ushort* wembTn = wbf + 60 * 4096;
  short8v wpre0, wpre1;

  for (int idx = t; idx < NTRI; idx += 256) tabL[idx] = tab_g[idx];
  if (t < 64)
    icntL[t] = 1.f / fmaxf((float)deg_g[min(nbase + t, NN - 1)], 1.f);
  WPRE_LOAD(wbf + 30 * 4096);
  __syncthreads();

  // ---- MFMA embed: smF = concat(f, fc_sum*icnt) @ Wemb2 ----
  #pragma unroll 1
  for (int h = 0; h < 2; ++h) {
    const int hb = h * 32;
    #pragma unroll 1
    for (int cc = t; cc < 384; cc += 256) {
      const int row = cc >> 2, seg = cc & 3;
      const int lel = (row * 43) >> 7, il = row - lel * 3;
      const int nc = min(nbase + hb + lel, NN - 1);
      const int k0 = seg * 16;
      float xv[16];
      if (seg < 2) {
        XV_LOAD16(f + nc * 96 + il * 32 + seg * 16);
      } else {
        XV_LOAD16(fcm + nc * 96 + il * 32 + (seg - 2) * 16);
        const float ic = icntL[hb + lel];
        #pragma unroll
        for (int m = 0; m < 16; ++m) xv[m] *= ic;
      }
      PACK_STORE16(&Aemb[row * SAN + k0]);
    }
    __syncthreads();
    #pragma unroll 1
    for (int job = w * 3; job < w * 3 + 3; ++job) {
      const int mt = job >> 1, nt = job & 1;
      f32x4 ac = (f32x4){0.f, 0.f, 0.f, 0.f};
      #pragma unroll
      for (int kb = 0; kb < 2; ++kb) {
        const bf16x8 av = *(const bf16x8*)&Aemb[(mt * 16 + ll) * SAN + kb * 32 + lh * 8];
        const bf16x8 bv = *(const bf16x8*)&wembTn[(nt * 16 + ll) * 64 + kb * 32 + lh * 8];
        ac = __builtin_amdgcn_mfma_f32_16x16x32_bf16(av, bv, ac, 0, 0, 0);
      }
      #pragma unroll
      for (int r = 0; r < 4; ++r) {
        const int rr = mt * 16 + lh * 4 + r;
        const int lel = (rr * 43) >> 7, il = rr - lel * 3;
        smF[(hb + lel) * SF + il * 32 + nt * 16 + ll] = ac[r];
      }
    }
    __syncthreads();
  }

  f32x4 acc[4];
  ZERO_ACC();
  float sumsq = 0.f;

  // ---- GEMM1: 11 K-stages ----
  #pragma unroll 1
  for (int T = 0; T < 11; ++T) {
    __syncthreads();
    WPRE_STORE();
    {
      const float* fr = smF + j * SF;
      float xv[16];
      if (T < 8) {
        TRI16(T * 64 + w * 16);
      } else if (T == 8) {
        if (w == 0) {
          TRI16(512);
        } else {
          #pragma unroll
          for (int m = 0; m < 16; ++m) xv[m] = 0.f;
        }
      } else if (T == 9) {
        XV_LOAD16(s + min(nbase + j, NN - 1) * 64 + w * 16);
      } else {
        XV_LOAD16(scm + min(nbase + j, NN - 1) * 64 + w * 16);
        const float ic = icntL[j];
        #pragma unroll
        for (int m = 0; m < 16; ++m) xv[m] *= ic;
      }
      PACK_STORE16(&Xl[j * STX + w * 16]);
    }
    __syncthreads();
    WPRE_LOAD(wbf + (31 + T) * 4096);
    MFMA_K64();
  }

  __syncthreads();
  red[w * 64 + j] = sumsq;
  #pragma unroll
  for (int nc = 0; nc < 4; ++nc) {
    const float bv = b1[nc * 16 + ll];
    #pragma unroll
    for (int r = 0; r < 4; ++r)
      Xl[(w * 16 + lh * 4 + r) * STX + nc * 16 + ll] = f2bf(fmaxf(acc[nc][r] + bv, 0.f));
  }
  WPRE_STORE();
  ZERO_ACC();
  __syncthreads();
  if (t < 64) {
    const float ss = red[t] + red[64 + t] + red[128 + t] + red[192 + t];
    iFn[t] = 1.f / (sqrtf(ss) + 1.f);
  }

  MFMA_K64();                        // GEMM2
  #pragma unroll
  for (int nc = 0; nc < 4; ++nc) {
    const float bv = b2[nc * 16 + ll];
    #pragma unroll
    for (int r = 0; r < 4; ++r)
      Xl[(w * 16 + lh * 4 + r) * STX + nc * 16 + ll] = f2bf(fmaxf(acc[nc][r] + bv, 0.f));
  }

  // ---- GEMM3: holder-side consume ----
  float fch[24];
  #pragma unroll
  for (int q = 0; q < 24; ++q) fch[q] = 0.f;
  float cs[16];
  float ifnr[4];

  #pragma unroll 1
  for (int nt = 0; nt < 17; ++nt) {
    __syncthreads();
    STAGE_W(wbf + (42 + nt) * 4096);
    float b3v[4];
    #pragma unroll
    for (int nc = 0; nc < 4; ++nc) b3v[nc] = b3[nt * 64 + nc * 16 + ll];
    __syncthreads();
    if (nt == 0) {
      #pragma unroll
      for (int r = 0; r < 4; ++r) ifnr[r] = iFn[w * 16 + lh * 4 + r];
    }
    ZERO_ACC();
    MFMA_K64();
    if (nt < 16) {
      CONSUME_NT();
    } else {
      #pragma unroll
      for (int nc = 0; nc < 4; ++nc)
        #pragma unroll
        for (int r = 0; r < 4; ++r)
          cs[nc * 4 + r] = (acc[nc][r] + b3v[nc]) * ifnr[r];
    }
  }

  // ---- stage F/S + residual writes ----
  __syncthreads();
  STAGE_FS();
  __syncthreads();

  #pragma unroll 1
  for (int m = 0; m < 16; ++m) {
    const int row = eb + m;
    const int n_m = nbase + row;
    if (n_m < NN) {
      of[n_m * 96 + j] = F[row * SFF + j] + f[n_m * 96 + j];
      if (j < 32)
        of[n_m * 96 + 64 + j] = F[row * SFF + 64 + j] + f[n_m * 96 + 64 + j];
      os[n_m * 64 + j] = S[row * 65 + j] + s[n_m * 64 + j];
    }
  }
}

extern "C" void kernel_launch(void* const* d_in, const int* in_sizes, int n_in,
                              void* d_out, int out_size, void* d_ws, size_t ws_size,
                              hipStream_t stream) {
  const float* f      = (const float*)d_in[0];
  const float* s      = (const float*)d_in[1];
  const float* edge_f = (const float*)d_in[2];
  const float* edge_s = (const float*)d_in[3];
  const float* Wemb1  = (const float*)d_in[4];
  const float* nW1 = (const float*)d_in[5];
  const float* nb1 = (const float*)d_in[6];
  const float* nW2 = (const float*)d_in[7];
  const float* nb2 = (const float*)d_in[8];
  const float* nW3 = (const float*)d_in[9];
  const float* nb3 = (const float*)d_in[10];
  const float* Wemb2 = (const float*)d_in[11];
  const float* sW1 = (const float*)d_in[12];
  const float* sb1 = (const float*)d_in[13];
  const float* sW2 = (const float*)d_in[14];
  const float* sb2 = (const float*)d_in[15];
  const float* sW3 = (const float*)d_in[16];
  const float* sb3 = (const float*)d_in[17];
  const int* eidx  = (const int*)d_in[18];

  float* of = (float*)d_out;               // [NN*96] ; holds fc sums pre-node
  float* os = of + (size_t)NN * 96;        // [NN*64] ; holds sc sums pre-node

  // ws: deg[NN] | cursor[NN] | start[NN] | sorted[NE] | wbf[61*4096] | tab[528]
  int* deg    = (int*)d_ws;
  int* cursor = deg + NN;
  int* start  = cursor + NN;
  int* sorted = start + NN;
  ushort* wbf = (ushort*)(sorted + NE);
  ushort* tab = wbf + 61 * 4096;

  hipMemsetAsync(deg, 0, (size_t)NN * 4, stream);
  hipMemsetAsync(d_out, 0, (size_t)NN * 160 * 4, stream);

  hipLaunchKernelGGL(sgnn_wconv, dim3((61 * 4096 + NTRI + 255) / 256), dim3(256),
                     0, stream, nW1, nW2, nW3, sW1, sW2, sW3, Wemb1, Wemb2,
                     wbf, tab);
  hipLaunchKernelGGL(sgnn_hist, dim3((NE + 255) / 256), dim3(256), 0, stream,
                     eidx, deg);
  hipLaunchKernelGGL(sgnn_scan, dim3(1), dim3(1024), 0, stream, deg, cursor, start);
  hipLaunchKernelGGL(sgnn_scatter, dim3((NE + 255) / 256), dim3(256), 0, stream,
                     eidx, cursor, sorted);
  hipLaunchKernelGGL(sgnn_edge, dim3(NE / 64), dim3(256), 0, stream,
                     f, s, edge_f, edge_s, nb1, nb2, nb3,
                     wbf, tab, eidx, sorted, start, deg,
                     of /*fc_sum*/, os /*sc_sum*/);
  hipLaunchKernelGGL(sgnn_node, dim3((NN + 63) / 64), dim3(256), 0, stream,
                     f, s, sb1, sb2, sb3,
                     wbf, tab, of /*fc sums*/, os /*sc sums*/, deg, of, os);
}